// Round 8
// baseline (290.368 us; speedup 1.0000x reference)
//
#include <hip/hip_runtime.h>
#include <math.h>

#define N_NODES 100000
#define N_EDGES 6400000
#define F_IN 36
#define HID 8
#define NCLS 2
#define NEG_SLOPE 0.2f

#define COARSE 256                        // nodes per coarse bucket (dst >> 8)
#define NBC 391                           // ceil(N_NODES/256)
#define CAPC 18432                        // max edges per coarse bucket (mean ~16368, +16 sigma)
#define NA_BLOCKS 1000                    // pass-A blocks
#define EPB (N_EDGES / NA_BLOCKS)         // 6400 edges per pass-A block (int4-aligned)
#define SHIFT1 8.0f                       // softmax shift (softmax is shift-invariant)
#define SHIFT2 16.0f

// ---------------- K0: per-node h1 = x@W1, s1s = h1.a_src, s1d = h1.a_dst ----
__global__ __launch_bounds__(256) void k0_node(
    const float* __restrict__ x, const float* __restrict__ W1,
    const float* __restrict__ a1s_g, const float* __restrict__ a1d_g,
    float* __restrict__ h1, float* __restrict__ s1s, float* __restrict__ s1d)
{
    __shared__ float sW[F_IN * HID];
    __shared__ float sas[HID], sad[HID];
    int tid = threadIdx.x;
    for (int i = tid; i < F_IN * HID; i += 256) sW[i] = W1[i];
    if (tid < HID) { sas[tid] = a1s_g[tid]; sad[tid] = a1d_g[tid]; }
    __syncthreads();

    int n = blockIdx.x * 256 + tid;
    if (n >= N_NODES) return;

    const float4* xp = (const float4*)(x + (size_t)n * F_IN);
    float h[HID];
#pragma unroll
    for (int f = 0; f < HID; ++f) h[f] = 0.f;
#pragma unroll
    for (int q = 0; q < F_IN / 4; ++q) {
        float4 v = xp[q];
        float vs[4] = {v.x, v.y, v.z, v.w};
#pragma unroll
        for (int j = 0; j < 4; ++j) {
            int k = q * 4 + j;
#pragma unroll
            for (int f = 0; f < HID; ++f) h[f] = fmaf(vs[j], sW[k * HID + f], h[f]);
        }
    }
    float ss = 0.f, sd = 0.f;
#pragma unroll
    for (int f = 0; f < HID; ++f) { ss = fmaf(h[f], sas[f], ss); sd = fmaf(h[f], sad[f], sd); }

    float4* hp = (float4*)(h1 + (size_t)n * HID);
    hp[0] = make_float4(h[0], h[1], h[2], h[3]);
    hp[1] = make_float4(h[4], h[5], h[6], h[7]);
    s1s[n] = ss;
    s1d[n] = sd;
}

// ---------------- KC: coarse-bucket histogram (LDS-privatized, 391 bins) ---
__global__ __launch_bounds__(256) void kc_hist(const int* __restrict__ dst, int* __restrict__ ccnt)
{
    __shared__ int lh[NBC];
    int tid = threadIdx.x;
    for (int i = tid; i < NBC; i += 256) lh[i] = 0;
    __syncthreads();
    const int4* dv = (const int4*)dst;
    int total4 = N_EDGES / 4;
    for (int i = blockIdx.x * 256 + tid; i < total4; i += gridDim.x * 256) {
        int4 d = dv[i];
        atomicAdd(&lh[d.x >> 8], 1);
        atomicAdd(&lh[d.y >> 8], 1);
        atomicAdd(&lh[d.z >> 8], 1);
        atomicAdd(&lh[d.w >> 8], 1);
    }
    __syncthreads();
    for (int i = tid; i < NBC; i += 256) if (lh[i]) atomicAdd(&ccnt[i], lh[i]);
}

// ---------------- K2b: scan coarse counts; init padded cursors -------------
__global__ __launch_bounds__(512) void k2b_cscan(const int* __restrict__ ccnt,
                                                 int* __restrict__ cbase, int* __restrict__ cursC)
{
    __shared__ int s[512];
    int tid = threadIdx.x;
    int v = (tid < NBC) ? ccnt[tid] : 0;
    s[tid] = v;
    __syncthreads();
    for (int off = 1; off < 512; off <<= 1) {
        int t = (tid >= off) ? s[tid - off] : 0;
        __syncthreads();
        s[tid] += t;
        __syncthreads();
    }
    int ex = s[tid] - v;
    if (tid < NBC) { cbase[tid] = ex; cursC[tid * 16] = ex; }
    if (tid == NBC) cbase[NBC] = ex;   // == N_EDGES
}

// ---------------- KA: coarse scatter (391 buckets, padded global cursors) --
__global__ __launch_bounds__(256) void kA_scatter(
    const int* __restrict__ src, const int* __restrict__ dst,
    int* __restrict__ cursC, unsigned int* __restrict__ bdata)
{
    __shared__ int lh[NBC];
    __shared__ int lc[NBC];
    int tid = threadIdx.x;
    for (int i = tid; i < NBC; i += 256) lh[i] = 0;
    __syncthreads();

    int e0 = blockIdx.x * EPB;
    const int4* sv = (const int4*)(src + e0);
    const int4* dv = (const int4*)(dst + e0);
    const int n4 = EPB / 4;                       // 1600

    for (int i = tid; i < n4; i += 256) {
        int4 d = dv[i];
        atomicAdd(&lh[d.x >> 8], 1);
        atomicAdd(&lh[d.y >> 8], 1);
        atomicAdd(&lh[d.z >> 8], 1);
        atomicAdd(&lh[d.w >> 8], 1);
    }
    __syncthreads();
    for (int b = tid; b < NBC; b += 256) {
        int c = lh[b];
        lc[b] = c ? atomicAdd(&cursC[b * 16], c) : 0;   // one 64B line per cursor
    }
    __syncthreads();
    for (int i = tid; i < n4; i += 256) {
        int4 d = dv[i];
        int4 s = sv[i];
        int b, p;
        b = d.x >> 8; p = atomicAdd(&lc[b], 1); bdata[p] = (unsigned)s.x | ((unsigned)(d.x & 255) << 17);
        b = d.y >> 8; p = atomicAdd(&lc[b], 1); bdata[p] = (unsigned)s.y | ((unsigned)(d.y & 255) << 17);
        b = d.z >> 8; p = atomicAdd(&lc[b], 1); bdata[p] = (unsigned)s.z | ((unsigned)(d.z & 255) << 17);
        b = d.w >> 8; p = atomicAdd(&lc[b], 1); bdata[p] = (unsigned)s.w | ((unsigned)(d.w & 255) << 17);
    }
}

// ---------------- KB: in-LDS node-granularity sort; emits nptr CSR ---------
__global__ __launch_bounds__(256) void kB_sort(
    const int* __restrict__ cbase, unsigned int* __restrict__ bdata,
    int* __restrict__ nptr)
{
    __shared__ unsigned int raw[CAPC];    // 72 KB
    __shared__ int cnt[COARSE];
    __shared__ int cur[COARSE];
    int tid = threadIdx.x;
    int c = blockIdx.x;
    int cb0 = cbase[c], cb1 = cbase[c + 1];
    int ne = cb1 - cb0;

    cnt[tid] = 0;
    __syncthreads();

    for (int i = tid; i < ne; i += 256) {
        unsigned pk = bdata[cb0 + i];
        raw[i] = pk;
        atomicAdd(&cnt[pk >> 17], 1);     // no return needed -> independent
    }
    __syncthreads();

    int v = cnt[tid];
    for (int off = 1; off < 256; off <<= 1) {
        int t = (tid >= off) ? cnt[tid - off] : 0;
        __syncthreads();
        cnt[tid] += t;
        __syncthreads();
    }
    int ex = cnt[tid] - v;                // exclusive within-bucket offset
    cur[tid] = ex;
    int nid = c * COARSE + tid;
    if (nid <= N_NODES) nptr[nid] = cb0 + ex;   // CSR pointer (nid==N_NODES -> N_EDGES)
    __syncthreads();

    for (int i = tid; i < ne; i += 256) {
        unsigned pk = raw[i];
        int loc = pk >> 17;
        int p = atomicAdd(&cur[loc], 1);
        bdata[cb0 + p] = pk & 0x1FFFF;    // node-sorted: store src only
    }
}

// ---------------- KAgg1: layer-1 CSR aggregation (16 threads/node, x2 MLP) -
__global__ __launch_bounds__(256) void kAgg1(
    const int* __restrict__ nptr, const unsigned int* __restrict__ bdata,
    const float* __restrict__ h1, const float* __restrict__ s1s, const float* __restrict__ s1d,
    const float* __restrict__ b1, const float* __restrict__ W2,
    const float* __restrict__ a2s, const float* __restrict__ a2d,
    float* __restrict__ h2, float* __restrict__ s2s, float* __restrict__ s2d)
{
    int gi = blockIdx.x * 256 + threadIdx.x;
    int n = gi >> 4, q = gi & 15;
    if (n >= N_NODES) return;

    int e0 = nptr[n], e1 = nptr[n + 1];
    float sdvn = s1d[n];
    float z = 0.f;
    float acc[HID];
#pragma unroll
    for (int f = 0; f < HID; ++f) acc[f] = 0.f;

    int j = e0 + q;
    for (; j + 16 < e1; j += 32) {
        int sA = bdata[j];
        int sB = bdata[j + 16];
        float rA = s1s[sA];
        float rB = s1s[sB];
        const float4* hpA = (const float4*)(h1 + (size_t)sA * HID);
        const float4* hpB = (const float4*)(h1 + (size_t)sB * HID);
        float4 a0 = hpA[0], a4 = hpA[1];
        float4 b0 = hpB[0], b4 = hpB[1];
        float eA = rA + sdvn; eA = (eA > 0.f) ? eA : NEG_SLOPE * eA;
        float eB = rB + sdvn; eB = (eB > 0.f) ? eB : NEG_SLOPE * eB;
        float pA = __expf(eA - SHIFT1);
        float pB = __expf(eB - SHIFT1);
        z += pA + pB;
        acc[0] += pA * a0.x + pB * b0.x;
        acc[1] += pA * a0.y + pB * b0.y;
        acc[2] += pA * a0.z + pB * b0.z;
        acc[3] += pA * a0.w + pB * b0.w;
        acc[4] += pA * a4.x + pB * b4.x;
        acc[5] += pA * a4.y + pB * b4.y;
        acc[6] += pA * a4.z + pB * b4.z;
        acc[7] += pA * a4.w + pB * b4.w;
    }
    if (j < e1) {
        int s = bdata[j];
        float e = s1s[s] + sdvn;
        e = (e > 0.f) ? e : NEG_SLOPE * e;
        float p = __expf(e - SHIFT1);
        const float4* hp = (const float4*)(h1 + (size_t)s * HID);
        float4 h0 = hp[0], h4 = hp[1];
        z += p;
        acc[0] += p * h0.x; acc[1] += p * h0.y; acc[2] += p * h0.z; acc[3] += p * h0.w;
        acc[4] += p * h4.x; acc[5] += p * h4.y; acc[6] += p * h4.z; acc[7] += p * h4.w;
    }

#pragma unroll
    for (int off = 1; off < 16; off <<= 1) {
        z += __shfl_xor(z, off);
#pragma unroll
        for (int f = 0; f < HID; ++f) acc[f] += __shfl_xor(acc[f], off);
    }

    if (q == 0) {
        float inv = 1.f / (z + 1e-16f);
        float c0 = 0.f, c1 = 0.f;
#pragma unroll
        for (int f = 0; f < HID; ++f) {
            float hr = fmaxf(acc[f] * inv + b1[f], 0.f);
            c0 = fmaf(hr, W2[f * NCLS + 0], c0);
            c1 = fmaf(hr, W2[f * NCLS + 1], c1);
        }
        ((float2*)h2)[n] = make_float2(c0, c1);
        s2s[n] = c0 * a2s[0] + c1 * a2s[1];
        s2d[n] = c0 * a2d[0] + c1 * a2d[1];
    }
}

// ---------------- KAgg2: layer-2 CSR aggregation (16 threads/node, x2 MLP) -
__global__ __launch_bounds__(256) void kAgg2(
    const int* __restrict__ nptr, const unsigned int* __restrict__ bdata,
    const float* __restrict__ h2, const float* __restrict__ s2s, const float* __restrict__ s2d,
    const float* __restrict__ b2, float* __restrict__ out)
{
    int gi = blockIdx.x * 256 + threadIdx.x;
    int n = gi >> 4, q = gi & 15;
    if (n >= N_NODES) return;

    int e0 = nptr[n], e1 = nptr[n + 1];
    float sdvn = s2d[n];
    float z = 0.f, a0 = 0.f, a1 = 0.f;

    int j = e0 + q;
    for (; j + 16 < e1; j += 32) {
        int sA = bdata[j];
        int sB = bdata[j + 16];
        float rA = s2s[sA];
        float rB = s2s[sB];
        float2 hA = ((const float2*)h2)[sA];
        float2 hB = ((const float2*)h2)[sB];
        float eA = rA + sdvn; eA = (eA > 0.f) ? eA : NEG_SLOPE * eA;
        float eB = rB + sdvn; eB = (eB > 0.f) ? eB : NEG_SLOPE * eB;
        float pA = __expf(eA - SHIFT2);
        float pB = __expf(eB - SHIFT2);
        z += pA + pB;
        a0 += pA * hA.x + pB * hB.x;
        a1 += pA * hA.y + pB * hB.y;
    }
    if (j < e1) {
        int s = bdata[j];
        float e = s2s[s] + sdvn;
        e = (e > 0.f) ? e : NEG_SLOPE * e;
        float p = __expf(e - SHIFT2);
        float2 hv = ((const float2*)h2)[s];
        z += p; a0 += p * hv.x; a1 += p * hv.y;
    }

#pragma unroll
    for (int off = 1; off < 16; off <<= 1) {
        z  += __shfl_xor(z, off);
        a0 += __shfl_xor(a0, off);
        a1 += __shfl_xor(a1, off);
    }

    if (q == 0) {
        float inv = 1.f / (z + 1e-16f);
        float o0 = a0 * inv + b2[0];
        float o1 = a1 * inv + b2[1];
        float mx = fmaxf(o0, o1);
        float lse = mx + __logf(__expf(o0 - mx) + __expf(o1 - mx));
        ((float2*)out)[n] = make_float2(o0 - lse, o1 - lse);
    }
}

// ---------------- host launch ----------------------------------------------
extern "C" void kernel_launch(void* const* d_in, const int* in_sizes, int n_in,
                              void* d_out, int out_size, void* d_ws, size_t ws_size,
                              hipStream_t stream) {
    const float* x   = (const float*)d_in[0];
    const float* W1  = (const float*)d_in[1];
    const float* a1s = (const float*)d_in[2];
    const float* a1d = (const float*)d_in[3];
    const float* b1  = (const float*)d_in[4];
    const float* W2  = (const float*)d_in[5];
    const float* a2s = (const float*)d_in[6];
    const float* a2d = (const float*)d_in[7];
    const float* b2  = (const float*)d_in[8];
    const int*   ei  = (const int*)d_in[9];
    const int* src = ei;
    const int* dst = ei + N_EDGES;

    char* ws = (char*)d_ws;
    float* h1    = (float*)(ws + 0);               // 3,200,000
    float* s1s   = (float*)(ws + 3200000);         //   400,000
    float* s1d   = (float*)(ws + 3600000);         //   400,000
    float* h2    = (float*)(ws + 4000000);         //   800,000
    float* s2s   = (float*)(ws + 4800000);         //   400,000
    float* s2d   = (float*)(ws + 5200000);         //   400,000
    int*   nptr  = (int*)  (ws + 5600000);         //   400,016
    int*   ccnt  = (int*)  (ws + 6000064);         //     1,564 -> pad
    int*   cbase = (int*)  (ws + 6001664);         //     1,568 -> pad
    int*   cursC = (int*)  (ws + 6003264);         //    25,024 (391 x 16 ints, 64B stride)
    unsigned int* bdata = (unsigned int*)(ws + 6028288);  // 25,600,000

    float* out = (float*)d_out;

    hipMemsetAsync(ccnt, 0, NBC * sizeof(int), stream);

    k0_node<<<(N_NODES + 255) / 256, 256, 0, stream>>>(x, W1, a1s, a1d, h1, s1s, s1d);
    kc_hist<<<512, 256, 0, stream>>>(dst, ccnt);
    k2b_cscan<<<1, 512, 0, stream>>>(ccnt, cbase, cursC);
    kA_scatter<<<NA_BLOCKS, 256, 0, stream>>>(src, dst, cursC, bdata);
    kB_sort<<<NBC, 256, 0, stream>>>(cbase, bdata, nptr);
    kAgg1<<<(N_NODES * 16 + 255) / 256, 256, 0, stream>>>(nptr, bdata, h1, s1s, s1d,
                                                          b1, W2, a2s, a2d, h2, s2s, s2d);
    kAgg2<<<(N_NODES * 16 + 255) / 256, 256, 0, stream>>>(nptr, bdata, h2, s2s, s2d, b2, out);
}

// Round 9
// 265.239 us; speedup vs baseline: 1.0947x; 1.0947x over previous
//
#include <hip/hip_runtime.h>
#include <math.h>

#define N_NODES 100000
#define N_EDGES 6400000
#define F_IN 36
#define HID 8
#define NCLS 2
#define NEG_SLOPE 0.2f

#define COARSE 256                        // nodes per coarse bucket (dst >> 8)
#define NBC 391                           // ceil(N_NODES/256)
#define CAPC 18432                        // max edges per coarse bucket (mean ~16368, +16 sigma)
#define CHUNK 8192                        // edges staged per kA block
#define NSTG ((N_EDGES + CHUNK - 1) / CHUNK)   // 782
#define SHIFT1 8.0f                       // softmax shift (softmax is shift-invariant)
#define SHIFT2 16.0f

// ---------------- K0: per-node h1 = x@W1, s1s = h1.a_src, s1d = h1.a_dst ----
__global__ __launch_bounds__(256) void k0_node(
    const float* __restrict__ x, const float* __restrict__ W1,
    const float* __restrict__ a1s_g, const float* __restrict__ a1d_g,
    float* __restrict__ h1, float* __restrict__ s1s, float* __restrict__ s1d)
{
    __shared__ float sW[F_IN * HID];
    __shared__ float sas[HID], sad[HID];
    int tid = threadIdx.x;
    for (int i = tid; i < F_IN * HID; i += 256) sW[i] = W1[i];
    if (tid < HID) { sas[tid] = a1s_g[tid]; sad[tid] = a1d_g[tid]; }
    __syncthreads();

    int n = blockIdx.x * 256 + tid;
    if (n >= N_NODES) return;

    const float4* xp = (const float4*)(x + (size_t)n * F_IN);
    float h[HID];
#pragma unroll
    for (int f = 0; f < HID; ++f) h[f] = 0.f;
#pragma unroll
    for (int q = 0; q < F_IN / 4; ++q) {
        float4 v = xp[q];
        float vs[4] = {v.x, v.y, v.z, v.w};
#pragma unroll
        for (int j = 0; j < 4; ++j) {
            int k = q * 4 + j;
#pragma unroll
            for (int f = 0; f < HID; ++f) h[f] = fmaf(vs[j], sW[k * HID + f], h[f]);
        }
    }
    float ss = 0.f, sd = 0.f;
#pragma unroll
    for (int f = 0; f < HID; ++f) { ss = fmaf(h[f], sas[f], ss); sd = fmaf(h[f], sad[f], sd); }

    float4* hp = (float4*)(h1 + (size_t)n * HID);
    hp[0] = make_float4(h[0], h[1], h[2], h[3]);
    hp[1] = make_float4(h[4], h[5], h[6], h[7]);
    s1s[n] = ss;
    s1d[n] = sd;
}

// ---------------- KC: coarse-bucket histogram (LDS-privatized, 391 bins) ---
__global__ __launch_bounds__(256) void kc_hist(const int* __restrict__ dst, int* __restrict__ ccnt)
{
    __shared__ int lh[NBC];
    int tid = threadIdx.x;
    for (int i = tid; i < NBC; i += 256) lh[i] = 0;
    __syncthreads();
    const int4* dv = (const int4*)dst;
    int total4 = N_EDGES / 4;
    for (int i = blockIdx.x * 256 + tid; i < total4; i += gridDim.x * 256) {
        int4 d = dv[i];
        atomicAdd(&lh[d.x >> 8], 1);
        atomicAdd(&lh[d.y >> 8], 1);
        atomicAdd(&lh[d.z >> 8], 1);
        atomicAdd(&lh[d.w >> 8], 1);
    }
    __syncthreads();
    for (int i = tid; i < NBC; i += 256) if (lh[i]) atomicAdd(&ccnt[i], lh[i]);
}

// ---------------- K2b: scan coarse counts; init padded cursors -------------
__global__ __launch_bounds__(512) void k2b_cscan(const int* __restrict__ ccnt,
                                                 int* __restrict__ cbase, int* __restrict__ cursC)
{
    __shared__ int s[512];
    int tid = threadIdx.x;
    int v = (tid < NBC) ? ccnt[tid] : 0;
    s[tid] = v;
    __syncthreads();
    for (int off = 1; off < 512; off <<= 1) {
        int t = (tid >= off) ? s[tid - off] : 0;
        __syncthreads();
        s[tid] += t;
        __syncthreads();
    }
    int ex = s[tid] - v;
    if (tid < NBC) { cbase[tid] = ex; cursC[tid * 16] = ex; }
    if (tid == NBC) cbase[NBC] = ex;   // == N_EDGES
}

// ---------------- KA: staged scatter — LDS bucket-sort then coalesced flush
__global__ __launch_bounds__(256) void kA_stage(
    const int* __restrict__ src, const int* __restrict__ dst,
    int* __restrict__ cursC, unsigned int* __restrict__ bdata)
{
    __shared__ unsigned int stg[CHUNK];    // 32 KB
    __shared__ int lh[NBC];
    __shared__ int lstart[NBC];
    __shared__ int lcur[NBC];
    __shared__ int tbase[NBC];
    int tid = threadIdx.x;

    for (int i = tid; i < NBC; i += 256) lh[i] = 0;
    __syncthreads();

    int e0 = blockIdx.x * CHUNK;
    int ne = N_EDGES - e0; if (ne > CHUNK) ne = CHUNK;   // always multiple of 4
    int n4 = ne >> 2;
    const int4* dv = (const int4*)(dst + e0);
    const int4* sv = (const int4*)(src + e0);

    // pass 1: histogram
    for (int i = tid; i < n4; i += 256) {
        int4 d = dv[i];
        atomicAdd(&lh[d.x >> 8], 1);
        atomicAdd(&lh[d.y >> 8], 1);
        atomicAdd(&lh[d.z >> 8], 1);
        atomicAdd(&lh[d.w >> 8], 1);
    }
    __syncthreads();

    // wave-0 exclusive scan of 391 counts (7 per lane)
    if (tid < 64) {
        int base = tid * 7;
        int cnt[7];
        int s = 0;
#pragma unroll
        for (int k = 0; k < 7; ++k) {
            int b = base + k;
            cnt[k] = (b < NBC) ? lh[b] : 0;
            s += cnt[k];
        }
        int inc = s;
#pragma unroll
        for (int off = 1; off < 64; off <<= 1) {
            int t2 = __shfl_up(inc, off);
            if (tid >= off) inc += t2;
        }
        int ex = inc - s;
#pragma unroll
        for (int k = 0; k < 7; ++k) {
            int b = base + k;
            if (b < NBC) { lstart[b] = ex; lcur[b] = ex; ex += cnt[k]; }
        }
    }
    __syncthreads();

    // reserve global tickets — 391 independent padded-line atomics, in parallel;
    // latency overlaps with pass 2 below (tbase consumed only after next barrier)
    for (int b = tid; b < NBC; b += 256) {
        int c = lh[b];
        tbase[b] = c ? atomicAdd(&cursC[b * 16], c) : 0;
    }

    // pass 2: scatter into LDS bucket order
    for (int i = tid; i < n4; i += 256) {
        int4 d = dv[i];
        int4 s = sv[i];
        int b, p;
        b = d.x >> 8; p = atomicAdd(&lcur[b], 1); stg[p] = (unsigned)s.x | ((unsigned)(d.x & 255) << 17);
        b = d.y >> 8; p = atomicAdd(&lcur[b], 1); stg[p] = (unsigned)s.y | ((unsigned)(d.y & 255) << 17);
        b = d.z >> 8; p = atomicAdd(&lcur[b], 1); stg[p] = (unsigned)s.z | ((unsigned)(d.z & 255) << 17);
        b = d.w >> 8; p = atomicAdd(&lcur[b], 1); stg[p] = (unsigned)s.w | ((unsigned)(d.w & 255) << 17);
    }
    __syncthreads();

    // flush: consecutive lanes write consecutive addresses of one bucket run
    int wid = tid >> 6, lane = tid & 63;
    for (int b = wid; b < NBC; b += 4) {
        int c = lh[b], ls = lstart[b], tb = tbase[b];
        for (int i = lane; i < c; i += 64) bdata[tb + i] = stg[ls + i];
    }
}

// ---------------- KB: in-LDS node-granularity sort; emits nptr CSR ---------
__global__ __launch_bounds__(256) void kB_sort(
    const int* __restrict__ cbase, unsigned int* __restrict__ bdata,
    int* __restrict__ nptr)
{
    __shared__ unsigned int raw[CAPC];    // 72 KB
    __shared__ int cnt[COARSE];
    __shared__ int cur[COARSE];
    int tid = threadIdx.x;
    int c = blockIdx.x;
    int cb0 = cbase[c], cb1 = cbase[c + 1];
    int ne = cb1 - cb0;

    cnt[tid] = 0;
    __syncthreads();

    for (int i = tid; i < ne; i += 256) {
        unsigned pk = bdata[cb0 + i];
        raw[i] = pk;
        atomicAdd(&cnt[pk >> 17], 1);     // no return needed -> independent
    }
    __syncthreads();

    int v = cnt[tid];
    for (int off = 1; off < 256; off <<= 1) {
        int t = (tid >= off) ? cnt[tid - off] : 0;
        __syncthreads();
        cnt[tid] += t;
        __syncthreads();
    }
    int ex = cnt[tid] - v;                // exclusive within-bucket offset
    cur[tid] = ex;
    int nid = c * COARSE + tid;
    if (nid <= N_NODES) nptr[nid] = cb0 + ex;   // CSR pointer (nid==N_NODES -> N_EDGES)
    __syncthreads();

    for (int i = tid; i < ne; i += 256) {
        unsigned pk = raw[i];
        int loc = pk >> 17;
        int p = atomicAdd(&cur[loc], 1);
        bdata[cb0 + p] = pk & 0x1FFFF;    // node-sorted: store src only
    }
}

// ---------------- KAgg1: layer-1 CSR aggregation (16 threads/node, x2 MLP) -
__global__ __launch_bounds__(256) void kAgg1(
    const int* __restrict__ nptr, const unsigned int* __restrict__ bdata,
    const float* __restrict__ h1, const float* __restrict__ s1s, const float* __restrict__ s1d,
    const float* __restrict__ b1, const float* __restrict__ W2,
    const float* __restrict__ a2s, const float* __restrict__ a2d,
    float* __restrict__ h2, float* __restrict__ s2s, float* __restrict__ s2d)
{
    int gi = blockIdx.x * 256 + threadIdx.x;
    int n = gi >> 4, q = gi & 15;
    if (n >= N_NODES) return;

    int e0 = nptr[n], e1 = nptr[n + 1];
    float sdvn = s1d[n];
    float z = 0.f;
    float acc[HID];
#pragma unroll
    for (int f = 0; f < HID; ++f) acc[f] = 0.f;

    int j = e0 + q;
    for (; j + 16 < e1; j += 32) {
        int sA = bdata[j];
        int sB = bdata[j + 16];
        float rA = s1s[sA];
        float rB = s1s[sB];
        const float4* hpA = (const float4*)(h1 + (size_t)sA * HID);
        const float4* hpB = (const float4*)(h1 + (size_t)sB * HID);
        float4 a0 = hpA[0], a4 = hpA[1];
        float4 b0 = hpB[0], b4 = hpB[1];
        float eA = rA + sdvn; eA = (eA > 0.f) ? eA : NEG_SLOPE * eA;
        float eB = rB + sdvn; eB = (eB > 0.f) ? eB : NEG_SLOPE * eB;
        float pA = __expf(eA - SHIFT1);
        float pB = __expf(eB - SHIFT1);
        z += pA + pB;
        acc[0] += pA * a0.x + pB * b0.x;
        acc[1] += pA * a0.y + pB * b0.y;
        acc[2] += pA * a0.z + pB * b0.z;
        acc[3] += pA * a0.w + pB * b0.w;
        acc[4] += pA * a4.x + pB * b4.x;
        acc[5] += pA * a4.y + pB * b4.y;
        acc[6] += pA * a4.z + pB * b4.z;
        acc[7] += pA * a4.w + pB * b4.w;
    }
    if (j < e1) {
        int s = bdata[j];
        float e = s1s[s] + sdvn;
        e = (e > 0.f) ? e : NEG_SLOPE * e;
        float p = __expf(e - SHIFT1);
        const float4* hp = (const float4*)(h1 + (size_t)s * HID);
        float4 h0 = hp[0], h4 = hp[1];
        z += p;
        acc[0] += p * h0.x; acc[1] += p * h0.y; acc[2] += p * h0.z; acc[3] += p * h0.w;
        acc[4] += p * h4.x; acc[5] += p * h4.y; acc[6] += p * h4.z; acc[7] += p * h4.w;
    }

#pragma unroll
    for (int off = 1; off < 16; off <<= 1) {
        z += __shfl_xor(z, off);
#pragma unroll
        for (int f = 0; f < HID; ++f) acc[f] += __shfl_xor(acc[f], off);
    }

    if (q == 0) {
        float inv = 1.f / (z + 1e-16f);
        float c0 = 0.f, c1 = 0.f;
#pragma unroll
        for (int f = 0; f < HID; ++f) {
            float hr = fmaxf(acc[f] * inv + b1[f], 0.f);
            c0 = fmaf(hr, W2[f * NCLS + 0], c0);
            c1 = fmaf(hr, W2[f * NCLS + 1], c1);
        }
        ((float2*)h2)[n] = make_float2(c0, c1);
        s2s[n] = c0 * a2s[0] + c1 * a2s[1];
        s2d[n] = c0 * a2d[0] + c1 * a2d[1];
    }
}

// ---------------- KAgg2: layer-2 CSR aggregation (16 threads/node, x2 MLP) -
__global__ __launch_bounds__(256) void kAgg2(
    const int* __restrict__ nptr, const unsigned int* __restrict__ bdata,
    const float* __restrict__ h2, const float* __restrict__ s2s, const float* __restrict__ s2d,
    const float* __restrict__ b2, float* __restrict__ out)
{
    int gi = blockIdx.x * 256 + threadIdx.x;
    int n = gi >> 4, q = gi & 15;
    if (n >= N_NODES) return;

    int e0 = nptr[n], e1 = nptr[n + 1];
    float sdvn = s2d[n];
    float z = 0.f, a0 = 0.f, a1 = 0.f;

    int j = e0 + q;
    for (; j + 16 < e1; j += 32) {
        int sA = bdata[j];
        int sB = bdata[j + 16];
        float rA = s2s[sA];
        float rB = s2s[sB];
        float2 hA = ((const float2*)h2)[sA];
        float2 hB = ((const float2*)h2)[sB];
        float eA = rA + sdvn; eA = (eA > 0.f) ? eA : NEG_SLOPE * eA;
        float eB = rB + sdvn; eB = (eB > 0.f) ? eB : NEG_SLOPE * eB;
        float pA = __expf(eA - SHIFT2);
        float pB = __expf(eB - SHIFT2);
        z += pA + pB;
        a0 += pA * hA.x + pB * hB.x;
        a1 += pA * hA.y + pB * hB.y;
    }
    if (j < e1) {
        int s = bdata[j];
        float e = s2s[s] + sdvn;
        e = (e > 0.f) ? e : NEG_SLOPE * e;
        float p = __expf(e - SHIFT2);
        float2 hv = ((const float2*)h2)[s];
        z += p; a0 += p * hv.x; a1 += p * hv.y;
    }

#pragma unroll
    for (int off = 1; off < 16; off <<= 1) {
        z  += __shfl_xor(z, off);
        a0 += __shfl_xor(a0, off);
        a1 += __shfl_xor(a1, off);
    }

    if (q == 0) {
        float inv = 1.f / (z + 1e-16f);
        float o0 = a0 * inv + b2[0];
        float o1 = a1 * inv + b2[1];
        float mx = fmaxf(o0, o1);
        float lse = mx + __logf(__expf(o0 - mx) + __expf(o1 - mx));
        ((float2*)out)[n] = make_float2(o0 - lse, o1 - lse);
    }
}

// ---------------- host launch ----------------------------------------------
extern "C" void kernel_launch(void* const* d_in, const int* in_sizes, int n_in,
                              void* d_out, int out_size, void* d_ws, size_t ws_size,
                              hipStream_t stream) {
    const float* x   = (const float*)d_in[0];
    const float* W1  = (const float*)d_in[1];
    const float* a1s = (const float*)d_in[2];
    const float* a1d = (const float*)d_in[3];
    const float* b1  = (const float*)d_in[4];
    const float* W2  = (const float*)d_in[5];
    const float* a2s = (const float*)d_in[6];
    const float* a2d = (const float*)d_in[7];
    const float* b2  = (const float*)d_in[8];
    const int*   ei  = (const int*)d_in[9];
    const int* src = ei;
    const int* dst = ei + N_EDGES;

    char* ws = (char*)d_ws;
    float* h1    = (float*)(ws + 0);               // 3,200,000
    float* s1s   = (float*)(ws + 3200000);         //   400,000
    float* s1d   = (float*)(ws + 3600000);         //   400,000
    float* h2    = (float*)(ws + 4000000);         //   800,000
    float* s2s   = (float*)(ws + 4800000);         //   400,000
    float* s2d   = (float*)(ws + 5200000);         //   400,000
    int*   nptr  = (int*)  (ws + 5600000);         //   400,016
    int*   ccnt  = (int*)  (ws + 6000064);         //     1,564 -> pad
    int*   cbase = (int*)  (ws + 6001664);         //     1,568 -> pad
    int*   cursC = (int*)  (ws + 6003264);         //    25,024 (391 x 16 ints, 64B stride)
    unsigned int* bdata = (unsigned int*)(ws + 6028288);  // 25,600,000

    float* out = (float*)d_out;

    hipMemsetAsync(ccnt, 0, NBC * sizeof(int), stream);

    k0_node<<<(N_NODES + 255) / 256, 256, 0, stream>>>(x, W1, a1s, a1d, h1, s1s, s1d);
    kc_hist<<<512, 256, 0, stream>>>(dst, ccnt);
    k2b_cscan<<<1, 512, 0, stream>>>(ccnt, cbase, cursC);
    kA_stage<<<NSTG, 256, 0, stream>>>(src, dst, cursC, bdata);
    kB_sort<<<NBC, 256, 0, stream>>>(cbase, bdata, nptr);
    kAgg1<<<(N_NODES * 16 + 255) / 256, 256, 0, stream>>>(nptr, bdata, h1, s1s, s1d,
                                                          b1, W2, a2s, a2d, h2, s2s, s2d);
    kAgg2<<<(N_NODES * 16 + 255) / 256, 256, 0, stream>>>(nptr, bdata, h2, s2s, s2d, b2, out);
}

// Round 10
// 227.114 us; speedup vs baseline: 1.2785x; 1.1679x over previous
//
#include <hip/hip_runtime.h>
#include <math.h>

#define N_NODES 100000
#define N_EDGES 6400000
#define F_IN 36
#define HID 8
#define NCLS 2
#define NEG_SLOPE 0.2f

#define COARSE 256                        // nodes per coarse bucket (dst >> 8)
#define NBC 391                           // ceil(N_NODES/256)
#define CAPC 18432                        // max edges per coarse bucket (mean ~16368, +16 sigma)
#define CHUNK 8192                        // edges staged per kA block
#define NSTG ((N_EDGES + CHUNK - 1) / CHUNK)   // 782
#define SHIFT1 8.0f                       // softmax shift (softmax is shift-invariant)
#define SHIFT2 16.0f
#define R1 10                             // floats per rec1 record (40B stride)

// ---------------- K0: per-node rec1 = {s1s, h1[0..7], s1d} ------------------
__global__ __launch_bounds__(256) void k0_node(
    const float* __restrict__ x, const float* __restrict__ W1,
    const float* __restrict__ a1s_g, const float* __restrict__ a1d_g,
    float* __restrict__ rec1)
{
    __shared__ float sW[F_IN * HID];
    __shared__ float sas[HID], sad[HID];
    int tid = threadIdx.x;
    for (int i = tid; i < F_IN * HID; i += 256) sW[i] = W1[i];
    if (tid < HID) { sas[tid] = a1s_g[tid]; sad[tid] = a1d_g[tid]; }
    __syncthreads();

    int n = blockIdx.x * 256 + tid;
    if (n >= N_NODES) return;

    const float4* xp = (const float4*)(x + (size_t)n * F_IN);
    float h[HID];
#pragma unroll
    for (int f = 0; f < HID; ++f) h[f] = 0.f;
#pragma unroll
    for (int q = 0; q < F_IN / 4; ++q) {
        float4 v = xp[q];
        float vs[4] = {v.x, v.y, v.z, v.w};
#pragma unroll
        for (int j = 0; j < 4; ++j) {
            int k = q * 4 + j;
#pragma unroll
            for (int f = 0; f < HID; ++f) h[f] = fmaf(vs[j], sW[k * HID + f], h[f]);
        }
    }
    float ss = 0.f, sd = 0.f;
#pragma unroll
    for (int f = 0; f < HID; ++f) { ss = fmaf(h[f], sas[f], ss); sd = fmaf(h[f], sad[f], sd); }

    float2* rp = (float2*)(rec1 + (size_t)n * R1);   // 40B stride -> 8B aligned
    rp[0] = make_float2(ss,  h[0]);
    rp[1] = make_float2(h[1], h[2]);
    rp[2] = make_float2(h[3], h[4]);
    rp[3] = make_float2(h[5], h[6]);
    rp[4] = make_float2(h[7], sd);
}

// ---------------- KC: coarse-bucket histogram (LDS-privatized, 391 bins) ---
__global__ __launch_bounds__(256) void kc_hist(const int* __restrict__ dst, int* __restrict__ ccnt)
{
    __shared__ int lh[NBC];
    int tid = threadIdx.x;
    for (int i = tid; i < NBC; i += 256) lh[i] = 0;
    __syncthreads();
    const int4* dv = (const int4*)dst;
    int total4 = N_EDGES / 4;
    for (int i = blockIdx.x * 256 + tid; i < total4; i += gridDim.x * 256) {
        int4 d = dv[i];
        atomicAdd(&lh[d.x >> 8], 1);
        atomicAdd(&lh[d.y >> 8], 1);
        atomicAdd(&lh[d.z >> 8], 1);
        atomicAdd(&lh[d.w >> 8], 1);
    }
    __syncthreads();
    for (int i = tid; i < NBC; i += 256) if (lh[i]) atomicAdd(&ccnt[i], lh[i]);
}

// ---------------- K2b: scan coarse counts; init padded cursors -------------
__global__ __launch_bounds__(512) void k2b_cscan(const int* __restrict__ ccnt,
                                                 int* __restrict__ cbase, int* __restrict__ cursC)
{
    __shared__ int s[512];
    int tid = threadIdx.x;
    int v = (tid < NBC) ? ccnt[tid] : 0;
    s[tid] = v;
    __syncthreads();
    for (int off = 1; off < 512; off <<= 1) {
        int t = (tid >= off) ? s[tid - off] : 0;
        __syncthreads();
        s[tid] += t;
        __syncthreads();
    }
    int ex = s[tid] - v;
    if (tid < NBC) { cbase[tid] = ex; cursC[tid * 16] = ex; }
    if (tid == NBC) cbase[NBC] = ex;   // == N_EDGES
}

// ---------------- KA: staged scatter — LDS bucket-sort then coalesced flush
__global__ __launch_bounds__(256) void kA_stage(
    const int* __restrict__ src, const int* __restrict__ dst,
    int* __restrict__ cursC, unsigned int* __restrict__ bdata)
{
    __shared__ unsigned int stg[CHUNK];    // 32 KB
    __shared__ int lh[NBC];
    __shared__ int lstart[NBC];
    __shared__ int lcur[NBC];
    __shared__ int tbase[NBC];
    int tid = threadIdx.x;

    for (int i = tid; i < NBC; i += 256) lh[i] = 0;
    __syncthreads();

    int e0 = blockIdx.x * CHUNK;
    int ne = N_EDGES - e0; if (ne > CHUNK) ne = CHUNK;   // always multiple of 4
    int n4 = ne >> 2;
    const int4* dv = (const int4*)(dst + e0);
    const int4* sv = (const int4*)(src + e0);

    // pass 1: histogram
    for (int i = tid; i < n4; i += 256) {
        int4 d = dv[i];
        atomicAdd(&lh[d.x >> 8], 1);
        atomicAdd(&lh[d.y >> 8], 1);
        atomicAdd(&lh[d.z >> 8], 1);
        atomicAdd(&lh[d.w >> 8], 1);
    }
    __syncthreads();

    // wave-0 exclusive scan of 391 counts (7 per lane)
    if (tid < 64) {
        int base = tid * 7;
        int cnt[7];
        int s = 0;
#pragma unroll
        for (int k = 0; k < 7; ++k) {
            int b = base + k;
            cnt[k] = (b < NBC) ? lh[b] : 0;
            s += cnt[k];
        }
        int inc = s;
#pragma unroll
        for (int off = 1; off < 64; off <<= 1) {
            int t2 = __shfl_up(inc, off);
            if (tid >= off) inc += t2;
        }
        int ex = inc - s;
#pragma unroll
        for (int k = 0; k < 7; ++k) {
            int b = base + k;
            if (b < NBC) { lstart[b] = ex; lcur[b] = ex; ex += cnt[k]; }
        }
    }
    __syncthreads();

    // reserve global tickets — 391 independent padded-line atomics
    for (int b = tid; b < NBC; b += 256) {
        int c = lh[b];
        tbase[b] = c ? atomicAdd(&cursC[b * 16], c) : 0;
    }

    // pass 2: scatter into LDS bucket order
    for (int i = tid; i < n4; i += 256) {
        int4 d = dv[i];
        int4 s = sv[i];
        int b, p;
        b = d.x >> 8; p = atomicAdd(&lcur[b], 1); stg[p] = (unsigned)s.x | ((unsigned)(d.x & 255) << 17);
        b = d.y >> 8; p = atomicAdd(&lcur[b], 1); stg[p] = (unsigned)s.y | ((unsigned)(d.y & 255) << 17);
        b = d.z >> 8; p = atomicAdd(&lcur[b], 1); stg[p] = (unsigned)s.z | ((unsigned)(d.z & 255) << 17);
        b = d.w >> 8; p = atomicAdd(&lcur[b], 1); stg[p] = (unsigned)s.w | ((unsigned)(d.w & 255) << 17);
    }
    __syncthreads();

    // flush: consecutive lanes write consecutive addresses of one bucket run
    int wid = tid >> 6, lane = tid & 63;
    for (int b = wid; b < NBC; b += 4) {
        int c = lh[b], ls = lstart[b], tb = tbase[b];
        for (int i = lane; i < c; i += 64) bdata[tb + i] = stg[ls + i];
    }
}

// ---------------- KB: in-LDS node-granularity sort; emits nptr CSR ---------
__global__ __launch_bounds__(256) void kB_sort(
    const int* __restrict__ cbase, unsigned int* __restrict__ bdata,
    int* __restrict__ nptr)
{
    __shared__ unsigned int raw[CAPC];    // 72 KB
    __shared__ int cnt[COARSE];
    __shared__ int cur[COARSE];
    int tid = threadIdx.x;
    int c = blockIdx.x;
    int cb0 = cbase[c], cb1 = cbase[c + 1];
    int ne = cb1 - cb0;

    cnt[tid] = 0;
    __syncthreads();

    for (int i = tid; i < ne; i += 256) {
        unsigned pk = bdata[cb0 + i];
        raw[i] = pk;
        atomicAdd(&cnt[pk >> 17], 1);     // no return needed -> independent
    }
    __syncthreads();

    int v = cnt[tid];
    for (int off = 1; off < 256; off <<= 1) {
        int t = (tid >= off) ? cnt[tid - off] : 0;
        __syncthreads();
        cnt[tid] += t;
        __syncthreads();
    }
    int ex = cnt[tid] - v;                // exclusive within-bucket offset
    cur[tid] = ex;
    int nid = c * COARSE + tid;
    if (nid <= N_NODES) nptr[nid] = cb0 + ex;   // CSR pointer (nid==N_NODES -> N_EDGES)
    __syncthreads();

    for (int i = tid; i < ne; i += 256) {
        unsigned pk = raw[i];
        int loc = pk >> 17;
        int p = atomicAdd(&cur[loc], 1);
        bdata[cb0 + p] = pk & 0x1FFFF;    // node-sorted: store src only
    }
}

// ---------------- KAgg1: layer-1 agg, packed rec1 gathers ------------------
__global__ __launch_bounds__(256) void kAgg1(
    const int* __restrict__ nptr, const unsigned int* __restrict__ bdata,
    const float* __restrict__ rec1,
    const float* __restrict__ b1, const float* __restrict__ W2,
    const float* __restrict__ a2s, const float* __restrict__ a2d,
    float4* __restrict__ rec2)
{
    int gi = blockIdx.x * 256 + threadIdx.x;
    int n = gi >> 4, q = gi & 15;
    if (n >= N_NODES) return;

    int e0 = nptr[n], e1 = nptr[n + 1];
    float sdvn = rec1[(size_t)n * R1 + 9];
    float z = 0.f;
    float acc[HID];
#pragma unroll
    for (int f = 0; f < HID; ++f) acc[f] = 0.f;

    int j = e0 + q;
    for (; j + 16 < e1; j += 32) {
        int sA = bdata[j];
        int sB = bdata[j + 16];
        const float2* rA = (const float2*)(rec1 + (size_t)sA * R1);
        const float2* rB = (const float2*)(rec1 + (size_t)sB * R1);
        float2 a0 = rA[0], a1v = rA[1], a2v = rA[2], a3 = rA[3], a4 = rA[4];
        float2 b0 = rB[0], b1v = rB[1], b2v = rB[2], b3 = rB[3], b4 = rB[4];
        float eA = a0.x + sdvn; eA = (eA > 0.f) ? eA : NEG_SLOPE * eA;
        float eB = b0.x + sdvn; eB = (eB > 0.f) ? eB : NEG_SLOPE * eB;
        float pA = __expf(eA - SHIFT1);
        float pB = __expf(eB - SHIFT1);
        z += pA + pB;
        acc[0] += pA * a0.y  + pB * b0.y;
        acc[1] += pA * a1v.x + pB * b1v.x;
        acc[2] += pA * a1v.y + pB * b1v.y;
        acc[3] += pA * a2v.x + pB * b2v.x;
        acc[4] += pA * a2v.y + pB * b2v.y;
        acc[5] += pA * a3.x  + pB * b3.x;
        acc[6] += pA * a3.y  + pB * b3.y;
        acc[7] += pA * a4.x  + pB * b4.x;
    }
    if (j < e1) {
        int s = bdata[j];
        const float2* rp = (const float2*)(rec1 + (size_t)s * R1);
        float2 v0 = rp[0], v1 = rp[1], v2 = rp[2], v3 = rp[3], v4 = rp[4];
        float e = v0.x + sdvn;
        e = (e > 0.f) ? e : NEG_SLOPE * e;
        float p = __expf(e - SHIFT1);
        z += p;
        acc[0] += p * v0.y; acc[1] += p * v1.x; acc[2] += p * v1.y; acc[3] += p * v2.x;
        acc[4] += p * v2.y; acc[5] += p * v3.x; acc[6] += p * v3.y; acc[7] += p * v4.x;
    }

#pragma unroll
    for (int off = 1; off < 16; off <<= 1) {
        z += __shfl_xor(z, off);
#pragma unroll
        for (int f = 0; f < HID; ++f) acc[f] += __shfl_xor(acc[f], off);
    }

    if (q == 0) {
        float inv = 1.f / (z + 1e-16f);
        float c0 = 0.f, c1 = 0.f;
#pragma unroll
        for (int f = 0; f < HID; ++f) {
            float hr = fmaxf(acc[f] * inv + b1[f], 0.f);
            c0 = fmaf(hr, W2[f * NCLS + 0], c0);
            c1 = fmaf(hr, W2[f * NCLS + 1], c1);
        }
        float s2sv = c0 * a2s[0] + c1 * a2s[1];
        float s2dv = c0 * a2d[0] + c1 * a2d[1];
        rec2[n] = make_float4(s2sv, c0, c1, s2dv);
    }
}

// ---------------- KAgg2: layer-2 agg, 1 float4 gather per edge -------------
__global__ __launch_bounds__(256) void kAgg2(
    const int* __restrict__ nptr, const unsigned int* __restrict__ bdata,
    const float4* __restrict__ rec2,
    const float* __restrict__ b2, float* __restrict__ out)
{
    int gi = blockIdx.x * 256 + threadIdx.x;
    int n = gi >> 4, q = gi & 15;
    if (n >= N_NODES) return;

    int e0 = nptr[n], e1 = nptr[n + 1];
    float sdvn = rec2[n].w;
    float z = 0.f, a0 = 0.f, a1 = 0.f;

    int j = e0 + q;
    for (; j + 16 < e1; j += 32) {
        int sA = bdata[j];
        int sB = bdata[j + 16];
        float4 rA = rec2[sA];
        float4 rB = rec2[sB];
        float eA = rA.x + sdvn; eA = (eA > 0.f) ? eA : NEG_SLOPE * eA;
        float eB = rB.x + sdvn; eB = (eB > 0.f) ? eB : NEG_SLOPE * eB;
        float pA = __expf(eA - SHIFT2);
        float pB = __expf(eB - SHIFT2);
        z += pA + pB;
        a0 += pA * rA.y + pB * rB.y;
        a1 += pA * rA.z + pB * rB.z;
    }
    if (j < e1) {
        int s = bdata[j];
        float4 r = rec2[s];
        float e = r.x + sdvn;
        e = (e > 0.f) ? e : NEG_SLOPE * e;
        float p = __expf(e - SHIFT2);
        z += p; a0 += p * r.y; a1 += p * r.z;
    }

#pragma unroll
    for (int off = 1; off < 16; off <<= 1) {
        z  += __shfl_xor(z, off);
        a0 += __shfl_xor(a0, off);
        a1 += __shfl_xor(a1, off);
    }

    if (q == 0) {
        float inv = 1.f / (z + 1e-16f);
        float o0 = a0 * inv + b2[0];
        float o1 = a1 * inv + b2[1];
        float mx = fmaxf(o0, o1);
        float lse = mx + __logf(__expf(o0 - mx) + __expf(o1 - mx));
        ((float2*)out)[n] = make_float2(o0 - lse, o1 - lse);
    }
}

// ---------------- host launch ----------------------------------------------
extern "C" void kernel_launch(void* const* d_in, const int* in_sizes, int n_in,
                              void* d_out, int out_size, void* d_ws, size_t ws_size,
                              hipStream_t stream) {
    const float* x   = (const float*)d_in[0];
    const float* W1  = (const float*)d_in[1];
    const float* a1s = (const float*)d_in[2];
    const float* a1d = (const float*)d_in[3];
    const float* b1  = (const float*)d_in[4];
    const float* W2  = (const float*)d_in[5];
    const float* a2s = (const float*)d_in[6];
    const float* a2d = (const float*)d_in[7];
    const float* b2  = (const float*)d_in[8];
    const int*   ei  = (const int*)d_in[9];
    const int* src = ei;
    const int* dst = ei + N_EDGES;

    char* ws = (char*)d_ws;
    float*  rec1  = (float*) (ws + 0);             // 4,000,000 (100000 x 10 floats)
    float4* rec2  = (float4*)(ws + 4000000);       // 1,600,000 (100000 x 16B)
    int*    nptr  = (int*)   (ws + 5600000);       //   400,016
    int*    ccnt  = (int*)   (ws + 6000064);       //     1,564 -> pad
    int*    cbase = (int*)   (ws + 6001664);       //     1,568 -> pad
    int*    cursC = (int*)   (ws + 6003264);       //    25,024 (391 x 16 ints, 64B stride)
    unsigned int* bdata = (unsigned int*)(ws + 6028288);  // 25,600,000

    float* out = (float*)d_out;

    hipMemsetAsync(ccnt, 0, NBC * sizeof(int), stream);

    k0_node<<<(N_NODES + 255) / 256, 256, 0, stream>>>(x, W1, a1s, a1d, rec1);
    kc_hist<<<512, 256, 0, stream>>>(dst, ccnt);
    k2b_cscan<<<1, 512, 0, stream>>>(ccnt, cbase, cursC);
    kA_stage<<<NSTG, 256, 0, stream>>>(src, dst, cursC, bdata);
    kB_sort<<<NBC, 256, 0, stream>>>(cbase, bdata, nptr);
    kAgg1<<<(N_NODES * 16 + 255) / 256, 256, 0, stream>>>(nptr, bdata, rec1,
                                                          b1, W2, a2s, a2d, rec2);
    kAgg2<<<(N_NODES * 16 + 255) / 256, 256, 0, stream>>>(nptr, bdata, rec2, b2, out);
}

// Round 11
// 199.285 us; speedup vs baseline: 1.4570x; 1.1396x over previous
//
#include <hip/hip_runtime.h>
#include <math.h>

#define N_NODES 100000
#define N_EDGES 6400000
#define F_IN 36
#define HID 8
#define NCLS 2
#define NEG_SLOPE 0.2f

#define COARSE 256                        // nodes per coarse bucket (dst >> 8)
#define NBC 391                           // ceil(N_NODES/256)
#define CAPC 18432                        // max edges per coarse bucket (mean ~16368, +16 sigma)
#define CHUNK 8192                        // edges staged per kA block
#define NSTG ((N_EDGES + CHUNK - 1) / CHUNK)   // 782
#define SHIFT1 8.0f                       // softmax shift (softmax is shift-invariant)
#define SHIFT2 16.0f
#define R1 10                             // floats per rec1 record (40B stride)

// ------- K0: per-node rec1 = {s1s, h1[0..7], s1d}  +  fused dst histogram --
__global__ __launch_bounds__(256) void k0_node(
    const float* __restrict__ x, const float* __restrict__ W1,
    const float* __restrict__ a1s_g, const float* __restrict__ a1d_g,
    const int* __restrict__ dst,
    float* __restrict__ rec1, int* __restrict__ ccnt)
{
    __shared__ float sW[F_IN * HID];
    __shared__ float sas[HID], sad[HID];
    __shared__ int lh[NBC];
    int tid = threadIdx.x;
    for (int i = tid; i < F_IN * HID; i += 256) sW[i] = W1[i];
    for (int i = tid; i < NBC; i += 256) lh[i] = 0;
    if (tid < HID) { sas[tid] = a1s_g[tid]; sad[tid] = a1d_g[tid]; }
    __syncthreads();

    int n = blockIdx.x * 256 + tid;
    if (n < N_NODES) {
        const float4* xp = (const float4*)(x + (size_t)n * F_IN);
        float h[HID];
#pragma unroll
        for (int f = 0; f < HID; ++f) h[f] = 0.f;
#pragma unroll
        for (int q = 0; q < F_IN / 4; ++q) {
            float4 v = xp[q];
            float vs[4] = {v.x, v.y, v.z, v.w};
#pragma unroll
            for (int j = 0; j < 4; ++j) {
                int k = q * 4 + j;
#pragma unroll
                for (int f = 0; f < HID; ++f) h[f] = fmaf(vs[j], sW[k * HID + f], h[f]);
            }
        }
        float ss = 0.f, sd = 0.f;
#pragma unroll
        for (int f = 0; f < HID; ++f) { ss = fmaf(h[f], sas[f], ss); sd = fmaf(h[f], sad[f], sd); }

        float2* rp = (float2*)(rec1 + (size_t)n * R1);   // 40B stride -> 8B aligned
        rp[0] = make_float2(ss,  h[0]);
        rp[1] = make_float2(h[1], h[2]);
        rp[2] = make_float2(h[3], h[4]);
        rp[3] = make_float2(h[5], h[6]);
        rp[4] = make_float2(h[7], sd);
    }

    // fused coarse-bucket histogram over dst (grid-stride, all threads)
    const int4* dv = (const int4*)dst;
    int total4 = N_EDGES / 4;
    for (int i = blockIdx.x * 256 + tid; i < total4; i += gridDim.x * 256) {
        int4 d = dv[i];
        atomicAdd(&lh[d.x >> 8], 1);
        atomicAdd(&lh[d.y >> 8], 1);
        atomicAdd(&lh[d.z >> 8], 1);
        atomicAdd(&lh[d.w >> 8], 1);
    }
    __syncthreads();
    for (int i = tid; i < NBC; i += 256) if (lh[i]) atomicAdd(&ccnt[i], lh[i]);
}

// ---------------- K2b: scan coarse counts; init padded cursors -------------
__global__ __launch_bounds__(512) void k2b_cscan(const int* __restrict__ ccnt,
                                                 int* __restrict__ cbase, int* __restrict__ cursC)
{
    __shared__ int s[512];
    int tid = threadIdx.x;
    int v = (tid < NBC) ? ccnt[tid] : 0;
    s[tid] = v;
    __syncthreads();
    for (int off = 1; off < 512; off <<= 1) {
        int t = (tid >= off) ? s[tid - off] : 0;
        __syncthreads();
        s[tid] += t;
        __syncthreads();
    }
    int ex = s[tid] - v;
    if (tid < NBC) { cbase[tid] = ex; cursC[tid * 16] = ex; }
    if (tid == NBC) cbase[NBC] = ex;   // == N_EDGES
}

// ------- KA: staged scatter — LDS bucket-sort then coalesced flush (512T) --
__global__ __launch_bounds__(512) void kA_stage(
    const int* __restrict__ src, const int* __restrict__ dst,
    int* __restrict__ cursC, unsigned int* __restrict__ bdata)
{
    __shared__ unsigned int stg[CHUNK];    // 32 KB
    __shared__ int lh[NBC];
    __shared__ int lstart[NBC];
    __shared__ int lcur[NBC];
    __shared__ int tbase[NBC];
    int tid = threadIdx.x;

    for (int i = tid; i < NBC; i += 512) lh[i] = 0;
    __syncthreads();

    int e0 = blockIdx.x * CHUNK;
    int ne = N_EDGES - e0; if (ne > CHUNK) ne = CHUNK;   // always multiple of 4
    int n4 = ne >> 2;
    const int4* dv = (const int4*)(dst + e0);
    const int4* sv = (const int4*)(src + e0);

    // pass 1: histogram
    for (int i = tid; i < n4; i += 512) {
        int4 d = dv[i];
        atomicAdd(&lh[d.x >> 8], 1);
        atomicAdd(&lh[d.y >> 8], 1);
        atomicAdd(&lh[d.z >> 8], 1);
        atomicAdd(&lh[d.w >> 8], 1);
    }
    __syncthreads();

    // wave-0 exclusive scan of 391 counts (7 per lane)
    if (tid < 64) {
        int base = tid * 7;
        int cnt[7];
        int s = 0;
#pragma unroll
        for (int k = 0; k < 7; ++k) {
            int b = base + k;
            cnt[k] = (b < NBC) ? lh[b] : 0;
            s += cnt[k];
        }
        int inc = s;
#pragma unroll
        for (int off = 1; off < 64; off <<= 1) {
            int t2 = __shfl_up(inc, off);
            if (tid >= off) inc += t2;
        }
        int ex = inc - s;
#pragma unroll
        for (int k = 0; k < 7; ++k) {
            int b = base + k;
            if (b < NBC) { lstart[b] = ex; lcur[b] = ex; ex += cnt[k]; }
        }
    }
    __syncthreads();

    // reserve global tickets — 391 independent padded-line atomics
    for (int b = tid; b < NBC; b += 512) {
        int c = lh[b];
        tbase[b] = c ? atomicAdd(&cursC[b * 16], c) : 0;
    }

    // pass 2: scatter into LDS bucket order
    for (int i = tid; i < n4; i += 512) {
        int4 d = dv[i];
        int4 s = sv[i];
        int b, p;
        b = d.x >> 8; p = atomicAdd(&lcur[b], 1); stg[p] = (unsigned)s.x | ((unsigned)(d.x & 255) << 17);
        b = d.y >> 8; p = atomicAdd(&lcur[b], 1); stg[p] = (unsigned)s.y | ((unsigned)(d.y & 255) << 17);
        b = d.z >> 8; p = atomicAdd(&lcur[b], 1); stg[p] = (unsigned)s.z | ((unsigned)(d.z & 255) << 17);
        b = d.w >> 8; p = atomicAdd(&lcur[b], 1); stg[p] = (unsigned)s.w | ((unsigned)(d.w & 255) << 17);
    }
    __syncthreads();

    // flush: consecutive lanes write consecutive addresses of one bucket run
    int wid = tid >> 6, lane = tid & 63;
    for (int b = wid; b < NBC; b += 8) {
        int c = lh[b], ls = lstart[b], tb = tbase[b];
        for (int i = lane; i < c; i += 64) bdata[tb + i] = stg[ls + i];
    }
}

// ------- KB: in-LDS node-granularity sort; emits nptr CSR (512T) -----------
__global__ __launch_bounds__(512) void kB_sort(
    const int* __restrict__ cbase, unsigned int* __restrict__ bdata,
    int* __restrict__ nptr)
{
    __shared__ unsigned int raw[CAPC];    // 72 KB
    __shared__ int cnt[COARSE];
    __shared__ int sstart[COARSE];
    __shared__ int cur[COARSE];
    int tid = threadIdx.x;
    int c = blockIdx.x;
    int cb0 = cbase[c], cb1 = cbase[c + 1];
    int ne = cb1 - cb0;

    if (tid < COARSE) cnt[tid] = 0;
    __syncthreads();

    for (int i = tid; i < ne; i += 512) {
        unsigned pk = bdata[cb0 + i];
        raw[i] = pk;
        atomicAdd(&cnt[pk >> 17], 1);     // no return needed -> independent
    }
    __syncthreads();

    // wave-0 exclusive scan of 256 counts (4 per lane)
    if (tid < 64) {
        int base = tid * 4;
        int c0 = cnt[base], c1 = cnt[base + 1], c2 = cnt[base + 2], c3 = cnt[base + 3];
        int s = c0 + c1 + c2 + c3;
        int inc = s;
#pragma unroll
        for (int off = 1; off < 64; off <<= 1) {
            int t2 = __shfl_up(inc, off);
            if (tid >= off) inc += t2;
        }
        int ex = inc - s;
        sstart[base]     = ex; cur[base]     = ex; ex += c0;
        sstart[base + 1] = ex; cur[base + 1] = ex; ex += c1;
        sstart[base + 2] = ex; cur[base + 2] = ex; ex += c2;
        sstart[base + 3] = ex; cur[base + 3] = ex;
    }
    __syncthreads();

    if (tid < COARSE) {
        int nid = c * COARSE + tid;
        if (nid < N_NODES) nptr[nid] = cb0 + sstart[tid];
    }
    if (c == 0 && tid == 0) nptr[N_NODES] = N_EDGES;

    for (int i = tid; i < ne; i += 512) {
        unsigned pk = raw[i];
        int loc = pk >> 17;
        int p = atomicAdd(&cur[loc], 1);
        bdata[cb0 + p] = pk & 0x1FFFF;    // node-sorted: store src only
    }
}

// ---------------- KAgg1: layer-1 agg, packed rec1 gathers ------------------
__global__ __launch_bounds__(256) void kAgg1(
    const int* __restrict__ nptr, const unsigned int* __restrict__ bdata,
    const float* __restrict__ rec1,
    const float* __restrict__ b1, const float* __restrict__ W2,
    const float* __restrict__ a2s, const float* __restrict__ a2d,
    float4* __restrict__ rec2)
{
    int gi = blockIdx.x * 256 + threadIdx.x;
    int n = gi >> 4, q = gi & 15;
    if (n >= N_NODES) return;

    int e0 = nptr[n], e1 = nptr[n + 1];
    float sdvn = rec1[(size_t)n * R1 + 9];
    float z = 0.f;
    float acc[HID];
#pragma unroll
    for (int f = 0; f < HID; ++f) acc[f] = 0.f;

    int j = e0 + q;
    for (; j + 16 < e1; j += 32) {
        int sA = bdata[j];
        int sB = bdata[j + 16];
        const float2* rA = (const float2*)(rec1 + (size_t)sA * R1);
        const float2* rB = (const float2*)(rec1 + (size_t)sB * R1);
        float2 a0 = rA[0], a1v = rA[1], a2v = rA[2], a3 = rA[3], a4 = rA[4];
        float2 b0 = rB[0], b1v = rB[1], b2v = rB[2], b3 = rB[3], b4 = rB[4];
        float eA = a0.x + sdvn; eA = (eA > 0.f) ? eA : NEG_SLOPE * eA;
        float eB = b0.x + sdvn; eB = (eB > 0.f) ? eB : NEG_SLOPE * eB;
        float pA = __expf(eA - SHIFT1);
        float pB = __expf(eB - SHIFT1);
        z += pA + pB;
        acc[0] += pA * a0.y  + pB * b0.y;
        acc[1] += pA * a1v.x + pB * b1v.x;
        acc[2] += pA * a1v.y + pB * b1v.y;
        acc[3] += pA * a2v.x + pB * b2v.x;
        acc[4] += pA * a2v.y + pB * b2v.y;
        acc[5] += pA * a3.x  + pB * b3.x;
        acc[6] += pA * a3.y  + pB * b3.y;
        acc[7] += pA * a4.x  + pB * b4.x;
    }
    if (j < e1) {
        int s = bdata[j];
        const float2* rp = (const float2*)(rec1 + (size_t)s * R1);
        float2 v0 = rp[0], v1 = rp[1], v2 = rp[2], v3 = rp[3], v4 = rp[4];
        float e = v0.x + sdvn;
        e = (e > 0.f) ? e : NEG_SLOPE * e;
        float p = __expf(e - SHIFT1);
        z += p;
        acc[0] += p * v0.y; acc[1] += p * v1.x; acc[2] += p * v1.y; acc[3] += p * v2.x;
        acc[4] += p * v2.y; acc[5] += p * v3.x; acc[6] += p * v3.y; acc[7] += p * v4.x;
    }

#pragma unroll
    for (int off = 1; off < 16; off <<= 1) {
        z += __shfl_xor(z, off);
#pragma unroll
        for (int f = 0; f < HID; ++f) acc[f] += __shfl_xor(acc[f], off);
    }

    if (q == 0) {
        float inv = 1.f / (z + 1e-16f);
        float c0 = 0.f, c1 = 0.f;
#pragma unroll
        for (int f = 0; f < HID; ++f) {
            float hr = fmaxf(acc[f] * inv + b1[f], 0.f);
            c0 = fmaf(hr, W2[f * NCLS + 0], c0);
            c1 = fmaf(hr, W2[f * NCLS + 1], c1);
        }
        float s2sv = c0 * a2s[0] + c1 * a2s[1];
        float s2dv = c0 * a2d[0] + c1 * a2d[1];
        rec2[n] = make_float4(s2sv, c0, c1, s2dv);
    }
}

// ---------------- KAgg2: layer-2 agg, 1 float4 gather per edge -------------
__global__ __launch_bounds__(256) void kAgg2(
    const int* __restrict__ nptr, const unsigned int* __restrict__ bdata,
    const float4* __restrict__ rec2,
    const float* __restrict__ b2, float* __restrict__ out)
{
    int gi = blockIdx.x * 256 + threadIdx.x;
    int n = gi >> 4, q = gi & 15;
    if (n >= N_NODES) return;

    int e0 = nptr[n], e1 = nptr[n + 1];
    float sdvn = rec2[n].w;
    float z = 0.f, a0 = 0.f, a1 = 0.f;

    int j = e0 + q;
    for (; j + 16 < e1; j += 32) {
        int sA = bdata[j];
        int sB = bdata[j + 16];
        float4 rA = rec2[sA];
        float4 rB = rec2[sB];
        float eA = rA.x + sdvn; eA = (eA > 0.f) ? eA : NEG_SLOPE * eA;
        float eB = rB.x + sdvn; eB = (eB > 0.f) ? eB : NEG_SLOPE * eB;
        float pA = __expf(eA - SHIFT2);
        float pB = __expf(eB - SHIFT2);
        z += pA + pB;
        a0 += pA * rA.y + pB * rB.y;
        a1 += pA * rA.z + pB * rB.z;
    }
    if (j < e1) {
        int s = bdata[j];
        float4 r = rec2[s];
        float e = r.x + sdvn;
        e = (e > 0.f) ? e : NEG_SLOPE * e;
        float p = __expf(e - SHIFT2);
        z += p; a0 += p * r.y; a1 += p * r.z;
    }

#pragma unroll
    for (int off = 1; off < 16; off <<= 1) {
        z  += __shfl_xor(z, off);
        a0 += __shfl_xor(a0, off);
        a1 += __shfl_xor(a1, off);
    }

    if (q == 0) {
        float inv = 1.f / (z + 1e-16f);
        float o0 = a0 * inv + b2[0];
        float o1 = a1 * inv + b2[1];
        float mx = fmaxf(o0, o1);
        float lse = mx + __logf(__expf(o0 - mx) + __expf(o1 - mx));
        ((float2*)out)[n] = make_float2(o0 - lse, o1 - lse);
    }
}

// ---------------- host launch ----------------------------------------------
extern "C" void kernel_launch(void* const* d_in, const int* in_sizes, int n_in,
                              void* d_out, int out_size, void* d_ws, size_t ws_size,
                              hipStream_t stream) {
    const float* x   = (const float*)d_in[0];
    const float* W1  = (const float*)d_in[1];
    const float* a1s = (const float*)d_in[2];
    const float* a1d = (const float*)d_in[3];
    const float* b1  = (const float*)d_in[4];
    const float* W2  = (const float*)d_in[5];
    const float* a2s = (const float*)d_in[6];
    const float* a2d = (const float*)d_in[7];
    const float* b2  = (const float*)d_in[8];
    const int*   ei  = (const int*)d_in[9];
    const int* src = ei;
    const int* dst = ei + N_EDGES;

    char* ws = (char*)d_ws;
    float*  rec1  = (float*) (ws + 0);             // 4,000,000 (100000 x 10 floats)
    float4* rec2  = (float4*)(ws + 4000000);       // 1,600,000 (100000 x 16B)
    int*    nptr  = (int*)   (ws + 5600000);       //   400,016
    int*    ccnt  = (int*)   (ws + 6000064);       //     1,564 -> pad
    int*    cbase = (int*)   (ws + 6001664);       //     1,568 -> pad
    int*    cursC = (int*)   (ws + 6003264);       //    25,024 (391 x 16 ints, 64B stride)
    unsigned int* bdata = (unsigned int*)(ws + 6028288);  // 25,600,000

    float* out = (float*)d_out;

    hipMemsetAsync(ccnt, 0, NBC * sizeof(int), stream);

    k0_node<<<(N_NODES + 255) / 256, 256, 0, stream>>>(x, W1, a1s, a1d, dst, rec1, ccnt);
    k2b_cscan<<<1, 512, 0, stream>>>(ccnt, cbase, cursC);
    kA_stage<<<NSTG, 512, 0, stream>>>(src, dst, cursC, bdata);
    kB_sort<<<NBC, 512, 0, stream>>>(cbase, bdata, nptr);
    kAgg1<<<(N_NODES * 16 + 255) / 256, 256, 0, stream>>>(nptr, bdata, rec1,
                                                          b1, W2, a2s, a2d, rec2);
    kAgg2<<<(N_NODES * 16 + 255) / 256, 256, 0, stream>>>(nptr, bdata, rec2, b2, out);
}

// Round 12
// 182.361 us; speedup vs baseline: 1.5923x; 1.0928x over previous
//
#include <hip/hip_runtime.h>
#include <hip/hip_fp16.h>
#include <math.h>

#define N_NODES 100000
#define N_EDGES 6400000
#define F_IN 36
#define HID 8
#define NCLS 2
#define NEG_SLOPE 0.2f

#define COARSE 256                        // nodes per coarse bucket (dst >> 8)
#define NBC 391                           // ceil(N_NODES/256)
#define CAPC 18432                        // max edges per coarse bucket (mean ~16368, +16 sigma)
#define CHUNK 8192                        // edges staged per kA block
#define NSTG ((N_EDGES + CHUNK - 1) / CHUNK)   // 782
#define SHIFT1 8.0f                       // softmax shift (softmax is shift-invariant)
#define SHIFT2 16.0f

// rec1: 32B-aligned record per node: [0]=s1s f32, [1]=s1d f32, [2..5]=h0..h7 fp16 pairs, [6..7]=pad

static __device__ __forceinline__ unsigned pack2h(float a, float b) {
    __half2 h = __float22half2_rn(make_float2(a, b));
    return *reinterpret_cast<unsigned*>(&h);
}
static __device__ __forceinline__ float2 unpack2h(unsigned u) {
    __half2 h = *reinterpret_cast<__half2*>(&u);
    return __half22float2(h);
}

// ------- K0: per-node rec1 (packed)  +  fused dst histogram ----------------
__global__ __launch_bounds__(256) void k0_node(
    const float* __restrict__ x, const float* __restrict__ W1,
    const float* __restrict__ a1s_g, const float* __restrict__ a1d_g,
    const int* __restrict__ dst,
    unsigned* __restrict__ rec1, int* __restrict__ ccnt)
{
    __shared__ float sW[F_IN * HID];
    __shared__ float sas[HID], sad[HID];
    __shared__ int lh[NBC];
    int tid = threadIdx.x;
    for (int i = tid; i < F_IN * HID; i += 256) sW[i] = W1[i];
    for (int i = tid; i < NBC; i += 256) lh[i] = 0;
    if (tid < HID) { sas[tid] = a1s_g[tid]; sad[tid] = a1d_g[tid]; }
    __syncthreads();

    int n = blockIdx.x * 256 + tid;
    if (n < N_NODES) {
        const float4* xp = (const float4*)(x + (size_t)n * F_IN);
        float h[HID];
#pragma unroll
        for (int f = 0; f < HID; ++f) h[f] = 0.f;
#pragma unroll
        for (int q = 0; q < F_IN / 4; ++q) {
            float4 v = xp[q];
            float vs[4] = {v.x, v.y, v.z, v.w};
#pragma unroll
            for (int j = 0; j < 4; ++j) {
                int k = q * 4 + j;
#pragma unroll
                for (int f = 0; f < HID; ++f) h[f] = fmaf(vs[j], sW[k * HID + f], h[f]);
            }
        }
        float ss = 0.f, sd = 0.f;
#pragma unroll
        for (int f = 0; f < HID; ++f) { ss = fmaf(h[f], sas[f], ss); sd = fmaf(h[f], sad[f], sd); }

        uint4* rp = (uint4*)(rec1 + ((size_t)n << 3));   // 32B stride, aligned
        uint4 w0, w1;
        w0.x = __float_as_uint(ss);
        w0.y = __float_as_uint(sd);
        w0.z = pack2h(h[0], h[1]);
        w0.w = pack2h(h[2], h[3]);
        w1.x = pack2h(h[4], h[5]);
        w1.y = pack2h(h[6], h[7]);
        w1.z = 0u; w1.w = 0u;
        rp[0] = w0;
        rp[1] = w1;
    }

    // fused coarse-bucket histogram over dst (grid-stride, all threads)
    const int4* dv = (const int4*)dst;
    int total4 = N_EDGES / 4;
    for (int i = blockIdx.x * 256 + tid; i < total4; i += gridDim.x * 256) {
        int4 d = dv[i];
        atomicAdd(&lh[d.x >> 8], 1);
        atomicAdd(&lh[d.y >> 8], 1);
        atomicAdd(&lh[d.z >> 8], 1);
        atomicAdd(&lh[d.w >> 8], 1);
    }
    __syncthreads();
    for (int i = tid; i < NBC; i += 256) if (lh[i]) atomicAdd(&ccnt[i], lh[i]);
}

// ---------------- K2b: scan coarse counts; init padded cursors -------------
__global__ __launch_bounds__(512) void k2b_cscan(const int* __restrict__ ccnt,
                                                 int* __restrict__ cbase, int* __restrict__ cursC)
{
    __shared__ int s[512];
    int tid = threadIdx.x;
    int v = (tid < NBC) ? ccnt[tid] : 0;
    s[tid] = v;
    __syncthreads();
    for (int off = 1; off < 512; off <<= 1) {
        int t = (tid >= off) ? s[tid - off] : 0;
        __syncthreads();
        s[tid] += t;
        __syncthreads();
    }
    int ex = s[tid] - v;
    if (tid < NBC) { cbase[tid] = ex; cursC[tid * 16] = ex; }
    if (tid == NBC) cbase[NBC] = ex;   // == N_EDGES
}

// ------- KA: staged scatter — LDS bucket-sort then coalesced flush (512T) --
__global__ __launch_bounds__(512) void kA_stage(
    const int* __restrict__ src, const int* __restrict__ dst,
    int* __restrict__ cursC, unsigned int* __restrict__ bdata)
{
    __shared__ unsigned int stg[CHUNK];    // 32 KB
    __shared__ int lh[NBC];
    __shared__ int lstart[NBC];
    __shared__ int lcur[NBC];
    __shared__ int tbase[NBC];
    int tid = threadIdx.x;

    for (int i = tid; i < NBC; i += 512) lh[i] = 0;
    __syncthreads();

    int e0 = blockIdx.x * CHUNK;
    int ne = N_EDGES - e0; if (ne > CHUNK) ne = CHUNK;   // always multiple of 4
    int n4 = ne >> 2;
    const int4* dv = (const int4*)(dst + e0);
    const int4* sv = (const int4*)(src + e0);

    // pass 1: histogram
    for (int i = tid; i < n4; i += 512) {
        int4 d = dv[i];
        atomicAdd(&lh[d.x >> 8], 1);
        atomicAdd(&lh[d.y >> 8], 1);
        atomicAdd(&lh[d.z >> 8], 1);
        atomicAdd(&lh[d.w >> 8], 1);
    }
    __syncthreads();

    // wave-0 exclusive scan of 391 counts (7 per lane)
    if (tid < 64) {
        int base = tid * 7;
        int cnt[7];
        int s = 0;
#pragma unroll
        for (int k = 0; k < 7; ++k) {
            int b = base + k;
            cnt[k] = (b < NBC) ? lh[b] : 0;
            s += cnt[k];
        }
        int inc = s;
#pragma unroll
        for (int off = 1; off < 64; off <<= 1) {
            int t2 = __shfl_up(inc, off);
            if (tid >= off) inc += t2;
        }
        int ex = inc - s;
#pragma unroll
        for (int k = 0; k < 7; ++k) {
            int b = base + k;
            if (b < NBC) { lstart[b] = ex; lcur[b] = ex; ex += cnt[k]; }
        }
    }
    __syncthreads();

    // reserve global tickets — 391 independent padded-line atomics
    for (int b = tid; b < NBC; b += 512) {
        int c = lh[b];
        tbase[b] = c ? atomicAdd(&cursC[b * 16], c) : 0;
    }

    // pass 2: scatter into LDS bucket order
    for (int i = tid; i < n4; i += 512) {
        int4 d = dv[i];
        int4 s = sv[i];
        int b, p;
        b = d.x >> 8; p = atomicAdd(&lcur[b], 1); stg[p] = (unsigned)s.x | ((unsigned)(d.x & 255) << 17);
        b = d.y >> 8; p = atomicAdd(&lcur[b], 1); stg[p] = (unsigned)s.y | ((unsigned)(d.y & 255) << 17);
        b = d.z >> 8; p = atomicAdd(&lcur[b], 1); stg[p] = (unsigned)s.z | ((unsigned)(d.z & 255) << 17);
        b = d.w >> 8; p = atomicAdd(&lcur[b], 1); stg[p] = (unsigned)s.w | ((unsigned)(d.w & 255) << 17);
    }
    __syncthreads();

    // flush: consecutive lanes write consecutive addresses of one bucket run
    int wid = tid >> 6, lane = tid & 63;
    for (int b = wid; b < NBC; b += 8) {
        int c = lh[b], ls = lstart[b], tb = tbase[b];
        for (int i = lane; i < c; i += 64) bdata[tb + i] = stg[ls + i];
    }
}

// ------- KB: in-LDS node-granularity sort; emits nptr CSR (512T) -----------
__global__ __launch_bounds__(512) void kB_sort(
    const int* __restrict__ cbase, unsigned int* __restrict__ bdata,
    int* __restrict__ nptr)
{
    __shared__ unsigned int raw[CAPC];    // 72 KB
    __shared__ int cnt[COARSE];
    __shared__ int sstart[COARSE];
    __shared__ int cur[COARSE];
    int tid = threadIdx.x;
    int c = blockIdx.x;
    int cb0 = cbase[c], cb1 = cbase[c + 1];
    int ne = cb1 - cb0;

    if (tid < COARSE) cnt[tid] = 0;
    __syncthreads();

    for (int i = tid; i < ne; i += 512) {
        unsigned pk = bdata[cb0 + i];
        raw[i] = pk;
        atomicAdd(&cnt[pk >> 17], 1);     // no return needed -> independent
    }
    __syncthreads();

    // wave-0 exclusive scan of 256 counts (4 per lane)
    if (tid < 64) {
        int base = tid * 4;
        int c0 = cnt[base], c1 = cnt[base + 1], c2 = cnt[base + 2], c3 = cnt[base + 3];
        int s = c0 + c1 + c2 + c3;
        int inc = s;
#pragma unroll
        for (int off = 1; off < 64; off <<= 1) {
            int t2 = __shfl_up(inc, off);
            if (tid >= off) inc += t2;
        }
        int ex = inc - s;
        sstart[base]     = ex; cur[base]     = ex; ex += c0;
        sstart[base + 1] = ex; cur[base + 1] = ex; ex += c1;
        sstart[base + 2] = ex; cur[base + 2] = ex; ex += c2;
        sstart[base + 3] = ex; cur[base + 3] = ex;
    }
    __syncthreads();

    if (tid < COARSE) {
        int nid = c * COARSE + tid;
        if (nid < N_NODES) nptr[nid] = cb0 + sstart[tid];
    }
    if (c == 0 && tid == 0) nptr[N_NODES] = N_EDGES;

    for (int i = tid; i < ne; i += 512) {
        unsigned pk = raw[i];
        int loc = pk >> 17;
        int p = atomicAdd(&cur[loc], 1);
        bdata[cb0 + p] = pk & 0x1FFFF;    // node-sorted: store src only
    }
}

// ---------------- KAgg1: layer-1 agg, 1-line packed gathers ----------------
__global__ __launch_bounds__(256) void kAgg1(
    const int* __restrict__ nptr, const unsigned int* __restrict__ bdata,
    const unsigned* __restrict__ rec1,
    const float* __restrict__ b1, const float* __restrict__ W2,
    const float* __restrict__ a2s, const float* __restrict__ a2d,
    float4* __restrict__ rec2)
{
    int gi = blockIdx.x * 256 + threadIdx.x;
    int n = gi >> 4, q = gi & 15;
    if (n >= N_NODES) return;

    int e0 = nptr[n], e1 = nptr[n + 1];
    float sdvn = __uint_as_float(rec1[((size_t)n << 3) + 1]);
    float z = 0.f;
    float acc[HID];
#pragma unroll
    for (int f = 0; f < HID; ++f) acc[f] = 0.f;

    int j = e0 + q;
    for (; j + 16 < e1; j += 32) {
        int sA = bdata[j];
        int sB = bdata[j + 16];
        const uint4* rA = (const uint4*)(rec1 + ((size_t)sA << 3));
        const uint4* rB = (const uint4*)(rec1 + ((size_t)sB << 3));
        uint4 a0 = rA[0];
        uint2 a1u = *(const uint2*)(rA + 1);
        uint4 b0 = rB[0];
        uint2 b1u = *(const uint2*)(rB + 1);
        float eA = __uint_as_float(a0.x) + sdvn; eA = (eA > 0.f) ? eA : NEG_SLOPE * eA;
        float eB = __uint_as_float(b0.x) + sdvn; eB = (eB > 0.f) ? eB : NEG_SLOPE * eB;
        float pA = __expf(eA - SHIFT1);
        float pB = __expf(eB - SHIFT1);
        z += pA + pB;
        float2 fa01 = unpack2h(a0.z),  fa23 = unpack2h(a0.w);
        float2 fa45 = unpack2h(a1u.x), fa67 = unpack2h(a1u.y);
        float2 fb01 = unpack2h(b0.z),  fb23 = unpack2h(b0.w);
        float2 fb45 = unpack2h(b1u.x), fb67 = unpack2h(b1u.y);
        acc[0] += pA * fa01.x + pB * fb01.x;
        acc[1] += pA * fa01.y + pB * fb01.y;
        acc[2] += pA * fa23.x + pB * fb23.x;
        acc[3] += pA * fa23.y + pB * fb23.y;
        acc[4] += pA * fa45.x + pB * fb45.x;
        acc[5] += pA * fa45.y + pB * fb45.y;
        acc[6] += pA * fa67.x + pB * fb67.x;
        acc[7] += pA * fa67.y + pB * fb67.y;
    }
    if (j < e1) {
        int s = bdata[j];
        const uint4* rp = (const uint4*)(rec1 + ((size_t)s << 3));
        uint4 v0 = rp[0];
        uint2 v1 = *(const uint2*)(rp + 1);
        float e = __uint_as_float(v0.x) + sdvn;
        e = (e > 0.f) ? e : NEG_SLOPE * e;
        float p = __expf(e - SHIFT1);
        z += p;
        float2 f01 = unpack2h(v0.z), f23 = unpack2h(v0.w);
        float2 f45 = unpack2h(v1.x), f67 = unpack2h(v1.y);
        acc[0] += p * f01.x; acc[1] += p * f01.y;
        acc[2] += p * f23.x; acc[3] += p * f23.y;
        acc[4] += p * f45.x; acc[5] += p * f45.y;
        acc[6] += p * f67.x; acc[7] += p * f67.y;
    }

#pragma unroll
    for (int off = 1; off < 16; off <<= 1) {
        z += __shfl_xor(z, off);
#pragma unroll
        for (int f = 0; f < HID; ++f) acc[f] += __shfl_xor(acc[f], off);
    }

    if (q == 0) {
        float inv = 1.f / (z + 1e-16f);
        float c0 = 0.f, c1 = 0.f;
#pragma unroll
        for (int f = 0; f < HID; ++f) {
            float hr = fmaxf(acc[f] * inv + b1[f], 0.f);
            c0 = fmaf(hr, W2[f * NCLS + 0], c0);
            c1 = fmaf(hr, W2[f * NCLS + 1], c1);
        }
        float s2sv = c0 * a2s[0] + c1 * a2s[1];
        float s2dv = c0 * a2d[0] + c1 * a2d[1];
        rec2[n] = make_float4(s2sv, c0, c1, s2dv);
    }
}

// ---------------- KAgg2: layer-2 agg, 1 float4 gather per edge -------------
__global__ __launch_bounds__(256) void kAgg2(
    const int* __restrict__ nptr, const unsigned int* __restrict__ bdata,
    const float4* __restrict__ rec2,
    const float* __restrict__ b2, float* __restrict__ out)
{
    int gi = blockIdx.x * 256 + threadIdx.x;
    int n = gi >> 4, q = gi & 15;
    if (n >= N_NODES) return;

    int e0 = nptr[n], e1 = nptr[n + 1];
    float sdvn = rec2[n].w;
    float z = 0.f, a0 = 0.f, a1 = 0.f;

    int j = e0 + q;
    for (; j + 16 < e1; j += 32) {
        int sA = bdata[j];
        int sB = bdata[j + 16];
        float4 rA = rec2[sA];
        float4 rB = rec2[sB];
        float eA = rA.x + sdvn; eA = (eA > 0.f) ? eA : NEG_SLOPE * eA;
        float eB = rB.x + sdvn; eB = (eB > 0.f) ? eB : NEG_SLOPE * eB;
        float pA = __expf(eA - SHIFT2);
        float pB = __expf(eB - SHIFT2);
        z += pA + pB;
        a0 += pA * rA.y + pB * rB.y;
        a1 += pA * rA.z + pB * rB.z;
    }
    if (j < e1) {
        int s = bdata[j];
        float4 r = rec2[s];
        float e = r.x + sdvn;
        e = (e > 0.f) ? e : NEG_SLOPE * e;
        float p = __expf(e - SHIFT2);
        z += p; a0 += p * r.y; a1 += p * r.z;
    }

#pragma unroll
    for (int off = 1; off < 16; off <<= 1) {
        z  += __shfl_xor(z, off);
        a0 += __shfl_xor(a0, off);
        a1 += __shfl_xor(a1, off);
    }

    if (q == 0) {
        float inv = 1.f / (z + 1e-16f);
        float o0 = a0 * inv + b2[0];
        float o1 = a1 * inv + b2[1];
        float mx = fmaxf(o0, o1);
        float lse = mx + __logf(__expf(o0 - mx) + __expf(o1 - mx));
        ((float2*)out)[n] = make_float2(o0 - lse, o1 - lse);
    }
}

// ---------------- host launch ----------------------------------------------
extern "C" void kernel_launch(void* const* d_in, const int* in_sizes, int n_in,
                              void* d_out, int out_size, void* d_ws, size_t ws_size,
                              hipStream_t stream) {
    const float* x   = (const float*)d_in[0];
    const float* W1  = (const float*)d_in[1];
    const float* a1s = (const float*)d_in[2];
    const float* a1d = (const float*)d_in[3];
    const float* b1  = (const float*)d_in[4];
    const float* W2  = (const float*)d_in[5];
    const float* a2s = (const float*)d_in[6];
    const float* a2d = (const float*)d_in[7];
    const float* b2  = (const float*)d_in[8];
    const int*   ei  = (const int*)d_in[9];
    const int* src = ei;
    const int* dst = ei + N_EDGES;

    char* ws = (char*)d_ws;
    unsigned* rec1  = (unsigned*)(ws + 0);         // 3,200,000 (100000 x 32B)
    float4*   rec2  = (float4*)  (ws + 4000000);   // 1,600,000 (100000 x 16B)
    int*      nptr  = (int*)     (ws + 5600000);   //   400,016
    int*      ccnt  = (int*)     (ws + 6000064);   //     1,564 -> pad
    int*      cbase = (int*)     (ws + 6001664);   //     1,568 -> pad
    int*      cursC = (int*)     (ws + 6003264);   //    25,024 (391 x 16 ints, 64B stride)
    unsigned int* bdata = (unsigned int*)(ws + 6028288);  // 25,600,000

    float* out = (float*)d_out;

    hipMemsetAsync(ccnt, 0, NBC * sizeof(int), stream);

    k0_node<<<(N_NODES + 255) / 256, 256, 0, stream>>>(x, W1, a1s, a1d, dst, rec1, ccnt);
    k2b_cscan<<<1, 512, 0, stream>>>(ccnt, cbase, cursC);
    kA_stage<<<NSTG, 512, 0, stream>>>(src, dst, cursC, bdata);
    kB_sort<<<NBC, 512, 0, stream>>>(cbase, bdata, nptr);
    kAgg1<<<(N_NODES * 16 + 255) / 256, 256, 0, stream>>>(nptr, bdata, rec1,
                                                          b1, W2, a2s, a2d, rec2);
    kAgg2<<<(N_NODES * 16 + 255) / 256, 256, 0, stream>>>(nptr, bdata, rec2, b2, out);
}

// Round 13
// 182.027 us; speedup vs baseline: 1.5952x; 1.0018x over previous
//
#include <hip/hip_runtime.h>
#include <hip/hip_fp16.h>
#include <math.h>

#define N_NODES 100000
#define N_EDGES 6400000
#define F_IN 36
#define HID 8
#define NCLS 2
#define NEG_SLOPE 0.2f

#define COARSE 256                        // nodes per coarse bucket (dst >> 8)
#define NBC 391                           // ceil(N_NODES/256)
#define CAPC 18432                        // max edges per coarse bucket (mean ~16368, +16 sigma)
#define CHUNK 4096                        // edges staged per kA block
#define NSTG ((N_EDGES + CHUNK - 1) / CHUNK)   // 1563
#define SHIFT1 8.0f                       // softmax shift (softmax is shift-invariant)
#define SHIFT2 16.0f

// rec1: 32B-aligned record per node: [0]=s1s f32, [1]=s1d f32, [2..5]=h0..h7 fp16 pairs, [6..7]=pad

static __device__ __forceinline__ unsigned pack2h(float a, float b) {
    __half2 h = __float22half2_rn(make_float2(a, b));
    return *reinterpret_cast<unsigned*>(&h);
}
static __device__ __forceinline__ float2 unpack2h(unsigned u) {
    __half2 h = *reinterpret_cast<__half2*>(&u);
    return __half22float2(h);
}

// ------- K0: per-node rec1 (packed)  +  fused dst histogram ----------------
__global__ __launch_bounds__(256) void k0_node(
    const float* __restrict__ x, const float* __restrict__ W1,
    const float* __restrict__ a1s_g, const float* __restrict__ a1d_g,
    const int* __restrict__ dst,
    unsigned* __restrict__ rec1, int* __restrict__ ccnt)
{
    __shared__ float sW[F_IN * HID];
    __shared__ float sas[HID], sad[HID];
    __shared__ int lh[NBC];
    int tid = threadIdx.x;
    for (int i = tid; i < F_IN * HID; i += 256) sW[i] = W1[i];
    for (int i = tid; i < NBC; i += 256) lh[i] = 0;
    if (tid < HID) { sas[tid] = a1s_g[tid]; sad[tid] = a1d_g[tid]; }
    __syncthreads();

    int n = blockIdx.x * 256 + tid;
    if (n < N_NODES) {
        const float4* xp = (const float4*)(x + (size_t)n * F_IN);
        float h[HID];
#pragma unroll
        for (int f = 0; f < HID; ++f) h[f] = 0.f;
#pragma unroll
        for (int q = 0; q < F_IN / 4; ++q) {
            float4 v = xp[q];
            float vs[4] = {v.x, v.y, v.z, v.w};
#pragma unroll
            for (int j = 0; j < 4; ++j) {
                int k = q * 4 + j;
#pragma unroll
                for (int f = 0; f < HID; ++f) h[f] = fmaf(vs[j], sW[k * HID + f], h[f]);
            }
        }
        float ss = 0.f, sd = 0.f;
#pragma unroll
        for (int f = 0; f < HID; ++f) { ss = fmaf(h[f], sas[f], ss); sd = fmaf(h[f], sad[f], sd); }

        uint4* rp = (uint4*)(rec1 + ((size_t)n << 3));   // 32B stride, aligned
        uint4 w0, w1;
        w0.x = __float_as_uint(ss);
        w0.y = __float_as_uint(sd);
        w0.z = pack2h(h[0], h[1]);
        w0.w = pack2h(h[2], h[3]);
        w1.x = pack2h(h[4], h[5]);
        w1.y = pack2h(h[6], h[7]);
        w1.z = 0u; w1.w = 0u;
        rp[0] = w0;
        rp[1] = w1;
    }

    // fused coarse-bucket histogram over dst (grid-stride, all threads)
    const int4* dv = (const int4*)dst;
    int total4 = N_EDGES / 4;
    for (int i = blockIdx.x * 256 + tid; i < total4; i += gridDim.x * 256) {
        int4 d = dv[i];
        atomicAdd(&lh[d.x >> 8], 1);
        atomicAdd(&lh[d.y >> 8], 1);
        atomicAdd(&lh[d.z >> 8], 1);
        atomicAdd(&lh[d.w >> 8], 1);
    }
    __syncthreads();
    for (int i = tid; i < NBC; i += 256) if (lh[i]) atomicAdd(&ccnt[i], lh[i]);
}

// ---------------- K2b: scan coarse counts; init padded cursors -------------
__global__ __launch_bounds__(512) void k2b_cscan(const int* __restrict__ ccnt,
                                                 int* __restrict__ cbase, int* __restrict__ cursC)
{
    __shared__ int s[512];
    int tid = threadIdx.x;
    int v = (tid < NBC) ? ccnt[tid] : 0;
    s[tid] = v;
    __syncthreads();
    for (int off = 1; off < 512; off <<= 1) {
        int t = (tid >= off) ? s[tid - off] : 0;
        __syncthreads();
        s[tid] += t;
        __syncthreads();
    }
    int ex = s[tid] - v;
    if (tid < NBC) { cbase[tid] = ex; cursC[tid * 16] = ex; }
    if (tid == NBC) cbase[NBC] = ex;   // == N_EDGES
}

// ------- KA: staged scatter — regs -> LDS bucket-sort -> parallel flush ----
__global__ __launch_bounds__(512) void kA_stage(
    const int* __restrict__ src, const int* __restrict__ dst,
    int* __restrict__ cursC, unsigned int* __restrict__ bdata)
{
    __shared__ unsigned int stg[CHUNK];          // 16 KB
    __shared__ unsigned short aux[CHUNK];        //  8 KB (bucket id per slot)
    __shared__ int lh[NBC];
    __shared__ int lstart[NBC];
    __shared__ int lcur[NBC];
    __shared__ int tbase[NBC];
    int tid = threadIdx.x;

    for (int i = tid; i < NBC; i += 512) lh[i] = 0;
    __syncthreads();

    int e0 = blockIdx.x * CHUNK;
    int ne = N_EDGES - e0; if (ne > CHUNK) ne = CHUNK;   // always multiple of 4
    int n4 = ne >> 2;                                    // 1024 (or 512 tail)
    const int4* dv = (const int4*)(dst + e0);
    const int4* sv = (const int4*)(src + e0);

    // pass 1: load chunk into registers + histogram
    int4 d0, s0, d1, s1;
    bool v0 = (tid < n4), v1 = (tid + 512 < n4);
    if (v0) {
        d0 = dv[tid]; s0 = sv[tid];
        atomicAdd(&lh[d0.x >> 8], 1);
        atomicAdd(&lh[d0.y >> 8], 1);
        atomicAdd(&lh[d0.z >> 8], 1);
        atomicAdd(&lh[d0.w >> 8], 1);
    }
    if (v1) {
        d1 = dv[tid + 512]; s1 = sv[tid + 512];
        atomicAdd(&lh[d1.x >> 8], 1);
        atomicAdd(&lh[d1.y >> 8], 1);
        atomicAdd(&lh[d1.z >> 8], 1);
        atomicAdd(&lh[d1.w >> 8], 1);
    }
    __syncthreads();

    // wave-0 exclusive scan of 391 counts (7 per lane)
    if (tid < 64) {
        int base = tid * 7;
        int cnt[7];
        int s = 0;
#pragma unroll
        for (int k = 0; k < 7; ++k) {
            int b = base + k;
            cnt[k] = (b < NBC) ? lh[b] : 0;
            s += cnt[k];
        }
        int inc = s;
#pragma unroll
        for (int off = 1; off < 64; off <<= 1) {
            int t2 = __shfl_up(inc, off);
            if (tid >= off) inc += t2;
        }
        int ex = inc - s;
#pragma unroll
        for (int k = 0; k < 7; ++k) {
            int b = base + k;
            if (b < NBC) { lstart[b] = ex; lcur[b] = ex; ex += cnt[k]; }
        }
    }
    __syncthreads();

    // reserve global tickets — 391 independent padded-line atomics
    for (int b = tid; b < NBC; b += 512) {
        int c = lh[b];
        tbase[b] = c ? atomicAdd(&cursC[b * 16], c) : 0;
    }

    // pass 2: scatter registers into LDS bucket order (+ record bucket id)
    int b, p;
    if (v0) {
        b = d0.x >> 8; p = atomicAdd(&lcur[b], 1); stg[p] = (unsigned)s0.x | ((unsigned)(d0.x & 255) << 17); aux[p] = (unsigned short)b;
        b = d0.y >> 8; p = atomicAdd(&lcur[b], 1); stg[p] = (unsigned)s0.y | ((unsigned)(d0.y & 255) << 17); aux[p] = (unsigned short)b;
        b = d0.z >> 8; p = atomicAdd(&lcur[b], 1); stg[p] = (unsigned)s0.z | ((unsigned)(d0.z & 255) << 17); aux[p] = (unsigned short)b;
        b = d0.w >> 8; p = atomicAdd(&lcur[b], 1); stg[p] = (unsigned)s0.w | ((unsigned)(d0.w & 255) << 17); aux[p] = (unsigned short)b;
    }
    if (v1) {
        b = d1.x >> 8; p = atomicAdd(&lcur[b], 1); stg[p] = (unsigned)s1.x | ((unsigned)(d1.x & 255) << 17); aux[p] = (unsigned short)b;
        b = d1.y >> 8; p = atomicAdd(&lcur[b], 1); stg[p] = (unsigned)s1.y | ((unsigned)(d1.y & 255) << 17); aux[p] = (unsigned short)b;
        b = d1.z >> 8; p = atomicAdd(&lcur[b], 1); stg[p] = (unsigned)s1.z | ((unsigned)(d1.z & 255) << 17); aux[p] = (unsigned short)b;
        b = d1.w >> 8; p = atomicAdd(&lcur[b], 1); stg[p] = (unsigned)s1.w | ((unsigned)(d1.w & 255) << 17); aux[p] = (unsigned short)b;
    }
    __syncthreads();

    // flush: every lane active; consecutive i within a run -> consecutive bdata
    for (int i = tid; i < ne; i += 512) {
        int bb = aux[i];
        bdata[tbase[bb] + (i - lstart[bb])] = stg[i];
    }
}

// ------- KB: in-LDS node-granularity sort; emits nptr CSR (512T) -----------
__global__ __launch_bounds__(512) void kB_sort(
    const int* __restrict__ cbase, unsigned int* __restrict__ bdata,
    int* __restrict__ nptr)
{
    __shared__ unsigned int raw[CAPC];    // 72 KB
    __shared__ int cnt[COARSE];
    __shared__ int sstart[COARSE];
    __shared__ int cur[COARSE];
    int tid = threadIdx.x;
    int c = blockIdx.x;
    int cb0 = cbase[c], cb1 = cbase[c + 1];
    int ne = cb1 - cb0;

    if (tid < COARSE) cnt[tid] = 0;
    __syncthreads();

    for (int i = tid; i < ne; i += 512) {
        unsigned pk = bdata[cb0 + i];
        raw[i] = pk;
        atomicAdd(&cnt[pk >> 17], 1);     // no return needed -> independent
    }
    __syncthreads();

    // wave-0 exclusive scan of 256 counts (4 per lane)
    if (tid < 64) {
        int base = tid * 4;
        int c0 = cnt[base], c1 = cnt[base + 1], c2 = cnt[base + 2], c3 = cnt[base + 3];
        int s = c0 + c1 + c2 + c3;
        int inc = s;
#pragma unroll
        for (int off = 1; off < 64; off <<= 1) {
            int t2 = __shfl_up(inc, off);
            if (tid >= off) inc += t2;
        }
        int ex = inc - s;
        sstart[base]     = ex; cur[base]     = ex; ex += c0;
        sstart[base + 1] = ex; cur[base + 1] = ex; ex += c1;
        sstart[base + 2] = ex; cur[base + 2] = ex; ex += c2;
        sstart[base + 3] = ex; cur[base + 3] = ex;
    }
    __syncthreads();

    if (tid < COARSE) {
        int nid = c * COARSE + tid;
        if (nid < N_NODES) nptr[nid] = cb0 + sstart[tid];
    }
    if (c == 0 && tid == 0) nptr[N_NODES] = N_EDGES;

    for (int i = tid; i < ne; i += 512) {
        unsigned pk = raw[i];
        int loc = pk >> 17;
        int p = atomicAdd(&cur[loc], 1);
        bdata[cb0 + p] = pk & 0x1FFFF;    // node-sorted: store src only
    }
}

// ---------------- KAgg1: layer-1 agg, 1-line packed gathers ----------------
__global__ __launch_bounds__(256) void kAgg1(
    const int* __restrict__ nptr, const unsigned int* __restrict__ bdata,
    const unsigned* __restrict__ rec1,
    const float* __restrict__ b1, const float* __restrict__ W2,
    const float* __restrict__ a2s, const float* __restrict__ a2d,
    float4* __restrict__ rec2)
{
    int gi = blockIdx.x * 256 + threadIdx.x;
    int n = gi >> 4, q = gi & 15;
    if (n >= N_NODES) return;

    int e0 = nptr[n], e1 = nptr[n + 1];
    float sdvn = __uint_as_float(rec1[((size_t)n << 3) + 1]);
    float z = 0.f;
    float acc[HID];
#pragma unroll
    for (int f = 0; f < HID; ++f) acc[f] = 0.f;

    int j = e0 + q;
    for (; j + 16 < e1; j += 32) {
        int sA = bdata[j];
        int sB = bdata[j + 16];
        const uint4* rA = (const uint4*)(rec1 + ((size_t)sA << 3));
        const uint4* rB = (const uint4*)(rec1 + ((size_t)sB << 3));
        uint4 a0 = rA[0];
        uint2 a1u = *(const uint2*)(rA + 1);
        uint4 b0 = rB[0];
        uint2 b1u = *(const uint2*)(rB + 1);
        float eA = __uint_as_float(a0.x) + sdvn; eA = (eA > 0.f) ? eA : NEG_SLOPE * eA;
        float eB = __uint_as_float(b0.x) + sdvn; eB = (eB > 0.f) ? eB : NEG_SLOPE * eB;
        float pA = __expf(eA - SHIFT1);
        float pB = __expf(eB - SHIFT1);
        z += pA + pB;
        float2 fa01 = unpack2h(a0.z),  fa23 = unpack2h(a0.w);
        float2 fa45 = unpack2h(a1u.x), fa67 = unpack2h(a1u.y);
        float2 fb01 = unpack2h(b0.z),  fb23 = unpack2h(b0.w);
        float2 fb45 = unpack2h(b1u.x), fb67 = unpack2h(b1u.y);
        acc[0] += pA * fa01.x + pB * fb01.x;
        acc[1] += pA * fa01.y + pB * fb01.y;
        acc[2] += pA * fa23.x + pB * fb23.x;
        acc[3] += pA * fa23.y + pB * fb23.y;
        acc[4] += pA * fa45.x + pB * fb45.x;
        acc[5] += pA * fa45.y + pB * fb45.y;
        acc[6] += pA * fa67.x + pB * fb67.x;
        acc[7] += pA * fa67.y + pB * fb67.y;
    }
    if (j < e1) {
        int s = bdata[j];
        const uint4* rp = (const uint4*)(rec1 + ((size_t)s << 3));
        uint4 v0 = rp[0];
        uint2 v1 = *(const uint2*)(rp + 1);
        float e = __uint_as_float(v0.x) + sdvn;
        e = (e > 0.f) ? e : NEG_SLOPE * e;
        float p = __expf(e - SHIFT1);
        z += p;
        float2 f01 = unpack2h(v0.z), f23 = unpack2h(v0.w);
        float2 f45 = unpack2h(v1.x), f67 = unpack2h(v1.y);
        acc[0] += p * f01.x; acc[1] += p * f01.y;
        acc[2] += p * f23.x; acc[3] += p * f23.y;
        acc[4] += p * f45.x; acc[5] += p * f45.y;
        acc[6] += p * f67.x; acc[7] += p * f67.y;
    }

#pragma unroll
    for (int off = 1; off < 16; off <<= 1) {
        z += __shfl_xor(z, off);
#pragma unroll
        for (int f = 0; f < HID; ++f) acc[f] += __shfl_xor(acc[f], off);
    }

    if (q == 0) {
        float inv = 1.f / (z + 1e-16f);
        float c0 = 0.f, c1 = 0.f;
#pragma unroll
        for (int f = 0; f < HID; ++f) {
            float hr = fmaxf(acc[f] * inv + b1[f], 0.f);
            c0 = fmaf(hr, W2[f * NCLS + 0], c0);
            c1 = fmaf(hr, W2[f * NCLS + 1], c1);
        }
        float s2sv = c0 * a2s[0] + c1 * a2s[1];
        float s2dv = c0 * a2d[0] + c1 * a2d[1];
        rec2[n] = make_float4(s2sv, c0, c1, s2dv);
    }
}

// ---------------- KAgg2: layer-2 agg, 1 float4 gather per edge -------------
__global__ __launch_bounds__(256) void kAgg2(
    const int* __restrict__ nptr, const unsigned int* __restrict__ bdata,
    const float4* __restrict__ rec2,
    const float* __restrict__ b2, float* __restrict__ out)
{
    int gi = blockIdx.x * 256 + threadIdx.x;
    int n = gi >> 4, q = gi & 15;
    if (n >= N_NODES) return;

    int e0 = nptr[n], e1 = nptr[n + 1];
    float sdvn = rec2[n].w;
    float z = 0.f, a0 = 0.f, a1 = 0.f;

    int j = e0 + q;
    for (; j + 16 < e1; j += 32) {
        int sA = bdata[j];
        int sB = bdata[j + 16];
        float4 rA = rec2[sA];
        float4 rB = rec2[sB];
        float eA = rA.x + sdvn; eA = (eA > 0.f) ? eA : NEG_SLOPE * eA;
        float eB = rB.x + sdvn; eB = (eB > 0.f) ? eB : NEG_SLOPE * eB;
        float pA = __expf(eA - SHIFT2);
        float pB = __expf(eB - SHIFT2);
        z += pA + pB;
        a0 += pA * rA.y + pB * rB.y;
        a1 += pA * rA.z + pB * rB.z;
    }
    if (j < e1) {
        int s = bdata[j];
        float4 r = rec2[s];
        float e = r.x + sdvn;
        e = (e > 0.f) ? e : NEG_SLOPE * e;
        float p = __expf(e - SHIFT2);
        z += p; a0 += p * r.y; a1 += p * r.z;
    }

#pragma unroll
    for (int off = 1; off < 16; off <<= 1) {
        z  += __shfl_xor(z, off);
        a0 += __shfl_xor(a0, off);
        a1 += __shfl_xor(a1, off);
    }

    if (q == 0) {
        float inv = 1.f / (z + 1e-16f);
        float o0 = a0 * inv + b2[0];
        float o1 = a1 * inv + b2[1];
        float mx = fmaxf(o0, o1);
        float lse = mx + __logf(__expf(o0 - mx) + __expf(o1 - mx));
        ((float2*)out)[n] = make_float2(o0 - lse, o1 - lse);
    }
}

// ---------------- host launch ----------------------------------------------
extern "C" void kernel_launch(void* const* d_in, const int* in_sizes, int n_in,
                              void* d_out, int out_size, void* d_ws, size_t ws_size,
                              hipStream_t stream) {
    const float* x   = (const float*)d_in[0];
    const float* W1  = (const float*)d_in[1];
    const float* a1s = (const float*)d_in[2];
    const float* a1d = (const float*)d_in[3];
    const float* b1  = (const float*)d_in[4];
    const float* W2  = (const float*)d_in[5];
    const float* a2s = (const float*)d_in[6];
    const float* a2d = (const float*)d_in[7];
    const float* b2  = (const float*)d_in[8];
    const int*   ei  = (const int*)d_in[9];
    const int* src = ei;
    const int* dst = ei + N_EDGES;

    char* ws = (char*)d_ws;
    unsigned* rec1  = (unsigned*)(ws + 0);         // 3,200,000 (100000 x 32B)
    float4*   rec2  = (float4*)  (ws + 4000000);   // 1,600,000 (100000 x 16B)
    int*      nptr  = (int*)     (ws + 5600000);   //   400,016
    int*      ccnt  = (int*)     (ws + 6000064);   //     1,564 -> pad
    int*      cbase = (int*)     (ws + 6001664);   //     1,568 -> pad
    int*      cursC = (int*)     (ws + 6003264);   //    25,024 (391 x 16 ints, 64B stride)
    unsigned int* bdata = (unsigned int*)(ws + 6028288);  // 25,600,000

    float* out = (float*)d_out;

    hipMemsetAsync(ccnt, 0, NBC * sizeof(int), stream);

    k0_node<<<(N_NODES + 255) / 256, 256, 0, stream>>>(x, W1, a1s, a1d, dst, rec1, ccnt);
    k2b_cscan<<<1, 512, 0, stream>>>(ccnt, cbase, cursC);
    kA_stage<<<NSTG, 512, 0, stream>>>(src, dst, cursC, bdata);
    kB_sort<<<NBC, 512, 0, stream>>>(cbase, bdata, nptr);
    kAgg1<<<(N_NODES * 16 + 255) / 256, 256, 0, stream>>>(nptr, bdata, rec1,
                                                          b1, W2, a2s, a2d, rec2);
    kAgg2<<<(N_NODES * 16 + 255) / 256, 256, 0, stream>>>(nptr, bdata, rec2, b2, out);
}